// Round 1
// baseline (2643.814 us; speedup 1.0000x reference)
//
#include <hip/hip_runtime.h>
#include <hip/hip_bf16.h>
#include <math.h>

#define T_SEQ 2048
#define C_DIM 2048
#define NH    32
#define NKV   8
#define DH    64
#define WIN   512

// ---------------------------------------------------------------------------
// fp32 tiled GEMM: C(MxN) = A(MxK) * B(KxN), all row-major.
// 64x64 tile, BK=16, 256 threads, 4x4 micro-tile per thread.
// ---------------------------------------------------------------------------
__global__ __launch_bounds__(256) void gemm_f32_kernel(
    const float* __restrict__ A, const float* __restrict__ B,
    float* __restrict__ C, int M, int N, int K) {
  __shared__ float As[16][68];  // [kk][row], padded so rows are 16B-aligned
  __shared__ float Bs[16][68];  // [kk][col]

  const int tid  = threadIdx.x;
  const int brow = blockIdx.y * 64;
  const int bcol = blockIdx.x * 64;
  const int tr = (tid >> 4) << 2;  // 0..60
  const int tc = (tid & 15) << 2;  // 0..60

  float acc[4][4] = {};

  for (int k0 = 0; k0 < K; k0 += 16) {
#pragma unroll
    for (int i = 0; i < 4; ++i) {
      int idx = tid + i * 256;            // 0..1023
      int r  = idx >> 4, kk = idx & 15;   // A tile: 64 rows x 16 k
      As[kk][r] = A[(size_t)(brow + r) * K + k0 + kk];
      int kr = idx >> 6, c = idx & 63;    // B tile: 16 k x 64 cols
      Bs[kr][c] = B[(size_t)(k0 + kr) * N + bcol + c];
    }
    __syncthreads();
#pragma unroll
    for (int kk = 0; kk < 16; ++kk) {
      float4 a4 = *(const float4*)&As[kk][tr];
      float4 b4 = *(const float4*)&Bs[kk][tc];
      const float a[4] = {a4.x, a4.y, a4.z, a4.w};
      const float b[4] = {b4.x, b4.y, b4.z, b4.w};
#pragma unroll
      for (int i = 0; i < 4; ++i)
#pragma unroll
        for (int j = 0; j < 4; ++j) acc[i][j] += a[i] * b[j];
    }
    __syncthreads();
  }

#pragma unroll
  for (int i = 0; i < 4; ++i)
#pragma unroll
    for (int j = 0; j < 4; ++j)
      C[(size_t)(brow + tr + i) * N + bcol + tc + j] = acc[i][j];
}

// ---------------------------------------------------------------------------
// In-place RoPE on a [T][n_heads*64] buffer. One thread per (t, h, j<32) pair.
// q'[j]    = q[j]*cos(t*f_j)  - q[j+32]*sin(t*f_j)
// q'[j+32] = q[j+32]*cos(...) + q[j]*sin(...)
// ---------------------------------------------------------------------------
__global__ void rope_kernel(float* __restrict__ X, int n_heads) {
  int idx = blockIdx.x * blockDim.x + threadIdx.x;
  int total = T_SEQ * n_heads * 32;
  if (idx >= total) return;
  int j = idx & 31;
  int h = (idx >> 5) % n_heads;
  int t = idx / (32 * n_heads);
  // inv_freq = 10000^(-2j/64); accurate path (angles reach ~2047 rad)
  float inv = powf(10000.0f, -(float)(2 * j) / 64.0f);
  float ang = (float)t * inv;
  float s, c;
  sincosf(ang, &s, &c);
  int base = (t * n_heads + h) * DH + j;
  float a = X[base], b = X[base + 32];
  X[base]      = a * c - b * s;
  X[base + 32] = b * c + a * s;
}

// ---------------------------------------------------------------------------
// Sliding-window causal GQA attention. One wave (64 lanes) per (t, h).
// Lane d owns dimension d of q / v-accumulator. Online softmax.
// Q layout [T][NH*64] (roped), K/V layout [T][NKV*64].
// ---------------------------------------------------------------------------
__global__ __launch_bounds__(64) void attn_kernel(
    const float* __restrict__ Q, const float* __restrict__ K,
    const float* __restrict__ V, float* __restrict__ O) {
  const int t    = blockIdx.x & (T_SEQ - 1);
  const int h    = blockIdx.x >> 11;   // / 2048
  const int lane = threadIdx.x;
  const int kvh  = h >> 2;             // n_rep = 4

  const float q = Q[(size_t)t * C_DIM + h * DH + lane];
  int lo = t - WIN;
  if (lo < 0) lo = 0;

  const float* Kp = K + kvh * DH + lane;
  const float* Vp = V + kvh * DH + lane;

  float m = -INFINITY, l = 0.0f, acc = 0.0f;
  for (int ki = lo; ki <= t; ++ki) {
    float s = q * Kp[(size_t)ki * (NKV * DH)];
    s += __shfl_xor(s, 1);
    s += __shfl_xor(s, 2);
    s += __shfl_xor(s, 4);
    s += __shfl_xor(s, 8);
    s += __shfl_xor(s, 16);
    s += __shfl_xor(s, 32);
    s *= 0.125f;  // 1/sqrt(64)
    float mn = fmaxf(m, s);
    float co = __expf(m - mn);   // m=-inf first iter -> 0, safe
    float p  = __expf(s - mn);
    l   = l * co + p;
    acc = acc * co + p * Vp[(size_t)ki * (NKV * DH)];
    m = mn;
  }
  O[(size_t)t * C_DIM + h * DH + lane] = acc / l;
}

// ---------------------------------------------------------------------------
extern "C" void kernel_launch(void* const* d_in, const int* in_sizes, int n_in,
                              void* d_out, int out_size, void* d_ws, size_t ws_size,
                              hipStream_t stream) {
  const float* x  = (const float*)d_in[0];
  const float* wq = (const float*)d_in[1];
  const float* wk = (const float*)d_in[2];
  const float* wv = (const float*)d_in[3];
  const float* wo = (const float*)d_in[4];
  float* out = (float*)d_out;

  float* Q  = (float*)d_ws;                 // [T][2048]
  float* Kb = Q  + (size_t)T_SEQ * C_DIM;   // [T][512]
  float* Vb = Kb + (size_t)T_SEQ * NKV * DH;
  float* Ab = Vb + (size_t)T_SEQ * NKV * DH; // attention out [T][2048]

  dim3 blk(256);
  // Q = x @ wq
  gemm_f32_kernel<<<dim3(C_DIM / 64, T_SEQ / 64), blk, 0, stream>>>(
      x, wq, Q, T_SEQ, C_DIM, C_DIM);
  // K = x @ wk, V = x @ wv
  gemm_f32_kernel<<<dim3((NKV * DH) / 64, T_SEQ / 64), blk, 0, stream>>>(
      x, wk, Kb, T_SEQ, NKV * DH, C_DIM);
  gemm_f32_kernel<<<dim3((NKV * DH) / 64, T_SEQ / 64), blk, 0, stream>>>(
      x, wv, Vb, T_SEQ, NKV * DH, C_DIM);
  // RoPE in place
  rope_kernel<<<(T_SEQ * NH * 32 + 255) / 256, 256, 0, stream>>>(Q, NH);
  rope_kernel<<<(T_SEQ * NKV * 32 + 255) / 256, 256, 0, stream>>>(Kb, NKV);
  // attention
  attn_kernel<<<T_SEQ * NH, 64, 0, stream>>>(Q, Kb, Vb, Ab);
  // out = Ab @ wo
  gemm_f32_kernel<<<dim3(C_DIM / 64, T_SEQ / 64), blk, 0, stream>>>(
      Ab, wo, out, T_SEQ, C_DIM, C_DIM);
}

// Round 2
// 820.947 us; speedup vs baseline: 3.2204x; 3.2204x over previous
//
#include <hip/hip_runtime.h>
#include <hip/hip_bf16.h>
#include <math.h>

#define T_SEQ 2048
#define C_DIM 2048
#define NH    32
#define NKV   8
#define DH    64
#define WIN   512

typedef __bf16 bf16x8 __attribute__((ext_vector_type(8)));
typedef float  f32x4  __attribute__((ext_vector_type(4)));

// ---------------------------------------------------------------------------
// fp32 tiled GEMM: C(MxN) = A(MxK) * B(KxN), all row-major. (unchanged)
// ---------------------------------------------------------------------------
__global__ __launch_bounds__(256) void gemm_f32_kernel(
    const float* __restrict__ A, const float* __restrict__ B,
    float* __restrict__ C, int M, int N, int K) {
  __shared__ float As[16][68];
  __shared__ float Bs[16][68];

  const int tid  = threadIdx.x;
  const int brow = blockIdx.y * 64;
  const int bcol = blockIdx.x * 64;
  const int tr = (tid >> 4) << 2;
  const int tc = (tid & 15) << 2;

  float acc[4][4] = {};

  for (int k0 = 0; k0 < K; k0 += 16) {
#pragma unroll
    for (int i = 0; i < 4; ++i) {
      int idx = tid + i * 256;
      int r  = idx >> 4, kk = idx & 15;
      As[kk][r] = A[(size_t)(brow + r) * K + k0 + kk];
      int kr = idx >> 6, c = idx & 63;
      Bs[kr][c] = B[(size_t)(k0 + kr) * N + bcol + c];
    }
    __syncthreads();
#pragma unroll
    for (int kk = 0; kk < 16; ++kk) {
      float4 a4 = *(const float4*)&As[kk][tr];
      float4 b4 = *(const float4*)&Bs[kk][tc];
      const float a[4] = {a4.x, a4.y, a4.z, a4.w};
      const float b[4] = {b4.x, b4.y, b4.z, b4.w};
#pragma unroll
      for (int i = 0; i < 4; ++i)
#pragma unroll
        for (int j = 0; j < 4; ++j) acc[i][j] += a[i] * b[j];
    }
    __syncthreads();
  }

#pragma unroll
  for (int i = 0; i < 4; ++i)
#pragma unroll
    for (int j = 0; j < 4; ++j)
      C[(size_t)(brow + tr + i) * N + bcol + tc + j] = acc[i][j];
}

// ---------------------------------------------------------------------------
// In-place RoPE on [T][n_heads*64]. (unchanged)
// ---------------------------------------------------------------------------
__global__ void rope_kernel(float* __restrict__ X, int n_heads) {
  int idx = blockIdx.x * blockDim.x + threadIdx.x;
  int total = T_SEQ * n_heads * 32;
  if (idx >= total) return;
  int j = idx & 31;
  int h = (idx >> 5) % n_heads;
  int t = idx / (32 * n_heads);
  float inv = powf(10000.0f, -(float)(2 * j) / 64.0f);
  float ang = (float)t * inv;
  float s, c;
  sincosf(ang, &s, &c);
  int base = (t * n_heads + h) * DH + j;
  float a = X[base], b = X[base + 32];
  X[base]      = a * c - b * s;
  X[base + 32] = b * c + a * s;
}

// ---------------------------------------------------------------------------
// Flash-style sliding-window GQA attention with bf16 MFMA.
// Block = 256 threads = 4 waves; block handles (head, 64-query tile);
// each wave owns 16 queries. Key tiles of 32.
// MFMA 16x16x32_bf16 layouts: A[l&15][(l>>4)*8+j], B[(l>>4)*8+j][l&15],
// D row=(l>>4)*4+r, col=l&15  (verified layouts, cdna4 guide §3).
// ---------------------------------------------------------------------------
__global__ __launch_bounds__(256) void attn_mfma_kernel(
    const float* __restrict__ Q, const float* __restrict__ K,
    const float* __restrict__ V, float* __restrict__ O) {
  __shared__ __bf16 K_lds[32][72];      // [key][d], +8 pad
  __shared__ __bf16 Vt[64][40];         // [d][key], +8 pad (transposed V)
  __shared__ __bf16 P_lds[4][16][40];   // per-wave P tile [q][k], +8 pad

  const int tid = threadIdx.x;
  const int l   = tid & 63;
  const int w   = tid >> 6;
  const int q0  = blockIdx.x * 64;
  const int h   = blockIdx.y;
  const int kvh = h >> 2;
  const int q0w = q0 + w * 16;

  const int lm = l & 15;      // A-row / D-col / B-col index
  const int lh = l >> 4;      // 0..3

  // Q fragments (registers, once per block)
  bf16x8 aq0, aq1;
  {
    const float* qp = Q + (size_t)(q0w + lm) * C_DIM + h * DH + lh * 8;
#pragma unroll
    for (int j = 0; j < 8; ++j) aq0[j] = (__bf16)qp[j];
#pragma unroll
    for (int j = 0; j < 8; ++j) aq1[j] = (__bf16)qp[32 + j];
  }

  f32x4 o_acc[4] = {};
  float m[4], lsum[4];
#pragma unroll
  for (int r = 0; r < 4; ++r) { m[r] = -1e30f; lsum[r] = 0.0f; }

  const int klo = (q0 - WIN) > 0 ? (q0 - WIN) : 0;
  const int stg_key = tid >> 3;        // 0..31
  const int stg_dp  = (tid & 7) * 8;   // 0..56

  for (int k0 = klo; k0 < q0 + 64; k0 += 32) {
    __syncthreads();   // previous-tile reads done before overwrite
    // ---- stage K tile (row-major bf16) and V tile (transposed bf16) ----
    {
      const float* ks = K + (size_t)(k0 + stg_key) * (NKV * DH) + kvh * DH + stg_dp;
      bf16x8 kb;
#pragma unroll
      for (int j = 0; j < 8; ++j) kb[j] = (__bf16)ks[j];
      *(bf16x8*)&K_lds[stg_key][stg_dp] = kb;

      const float* vs = V + (size_t)(k0 + stg_key) * (NKV * DH) + kvh * DH + stg_dp;
#pragma unroll
      for (int j = 0; j < 8; ++j) Vt[stg_dp + j][stg_key] = (__bf16)vs[j];
    }
    __syncthreads();

    // wave-level skip: tile disjoint from this wave's allowed key range
    if (k0 <= q0w + 15 && k0 + 31 >= q0w - WIN) {
      // ---- S = Q K^T (two 16-key groups, contraction over d=64) ----
      f32x4 s[2] = {};
#pragma unroll
      for (int kg = 0; kg < 2; ++kg) {
        bf16x8 kb0 = *(const bf16x8*)&K_lds[kg * 16 + lm][lh * 8];
        bf16x8 kb1 = *(const bf16x8*)&K_lds[kg * 16 + lm][32 + lh * 8];
        s[kg] = __builtin_amdgcn_mfma_f32_16x16x32_bf16(aq0, kb0, s[kg], 0, 0, 0);
        s[kg] = __builtin_amdgcn_mfma_f32_16x16x32_bf16(aq1, kb1, s[kg], 0, 0, 0);
      }

      // ---- mask + scale; per-row online softmax ----
      float sv0[4], sv1[4], tmax[4];
#pragma unroll
      for (int r = 0; r < 4; ++r) {
        int qr  = q0w + lh * 4 + r;
        int kc0 = k0 + lm;
        int kc1 = kc0 + 16;
        float a = s[0][r] * 0.125f;
        float b = s[1][r] * 0.125f;
        sv0[r] = (kc0 <= qr && kc0 + WIN >= qr) ? a : -1e30f;
        sv1[r] = (kc1 <= qr && kc1 + WIN >= qr) ? b : -1e30f;
        tmax[r] = fmaxf(sv0[r], sv1[r]);
      }
#pragma unroll
      for (int off = 1; off < 16; off <<= 1)
#pragma unroll
        for (int r = 0; r < 4; ++r)
          tmax[r] = fmaxf(tmax[r], __shfl_xor(tmax[r], off));

      float p0[4], p1[4];
#pragma unroll
      for (int r = 0; r < 4; ++r) {
        float mn = fmaxf(m[r], tmax[r]);
        float co = __expf(m[r] - mn);
        m[r] = mn;
        p0[r] = (sv0[r] > -1e29f) ? __expf(sv0[r] - mn) : 0.0f;
        p1[r] = (sv1[r] > -1e29f) ? __expf(sv1[r] - mn) : 0.0f;
        float ps = p0[r] + p1[r];
#pragma unroll
        for (int off = 1; off < 16; off <<= 1) ps += __shfl_xor(ps, off);
        lsum[r] = lsum[r] * co + ps;
#pragma unroll
        for (int dc = 0; dc < 4; ++dc) o_acc[dc][r] *= co;
      }

      // ---- P -> LDS (D-layout write), reread as A-layout fragment ----
#pragma unroll
      for (int r = 0; r < 4; ++r) {
        P_lds[w][lh * 4 + r][lm]      = (__bf16)p0[r];
        P_lds[w][lh * 4 + r][16 + lm] = (__bf16)p1[r];
      }
      bf16x8 pf = *(const bf16x8*)&P_lds[w][lm][lh * 8];

      // ---- O += P V (4 d-chunks of 16) ----
#pragma unroll
      for (int dc = 0; dc < 4; ++dc) {
        bf16x8 vb = *(const bf16x8*)&Vt[dc * 16 + lm][lh * 8];
        o_acc[dc] = __builtin_amdgcn_mfma_f32_16x16x32_bf16(pf, vb, o_acc[dc], 0, 0, 0);
      }
    }
  }

  // ---- epilogue: O / l ----
#pragma unroll
  for (int dc = 0; dc < 4; ++dc)
#pragma unroll
    for (int r = 0; r < 4; ++r) {
      int qr = q0w + lh * 4 + r;
      O[(size_t)qr * C_DIM + h * DH + dc * 16 + lm] = o_acc[dc][r] / lsum[r];
    }
}

// ---------------------------------------------------------------------------
extern "C" void kernel_launch(void* const* d_in, const int* in_sizes, int n_in,
                              void* d_out, int out_size, void* d_ws, size_t ws_size,
                              hipStream_t stream) {
  const float* x  = (const float*)d_in[0];
  const float* wq = (const float*)d_in[1];
  const float* wk = (const float*)d_in[2];
  const float* wv = (const float*)d_in[3];
  const float* wo = (const float*)d_in[4];
  float* out = (float*)d_out;

  float* Q  = (float*)d_ws;                 // [T][2048]
  float* Kb = Q  + (size_t)T_SEQ * C_DIM;   // [T][512]
  float* Vb = Kb + (size_t)T_SEQ * NKV * DH;
  float* Ab = Vb + (size_t)T_SEQ * NKV * DH; // attention out [T][2048]

  dim3 blk(256);
  gemm_f32_kernel<<<dim3(C_DIM / 64, T_SEQ / 64), blk, 0, stream>>>(
      x, wq, Q, T_SEQ, C_DIM, C_DIM);
  gemm_f32_kernel<<<dim3((NKV * DH) / 64, T_SEQ / 64), blk, 0, stream>>>(
      x, wk, Kb, T_SEQ, NKV * DH, C_DIM);
  gemm_f32_kernel<<<dim3((NKV * DH) / 64, T_SEQ / 64), blk, 0, stream>>>(
      x, wv, Vb, T_SEQ, NKV * DH, C_DIM);
  rope_kernel<<<(T_SEQ * NH * 32 + 255) / 256, 256, 0, stream>>>(Q, NH);
  rope_kernel<<<(T_SEQ * NKV * 32 + 255) / 256, 256, 0, stream>>>(Kb, NKV);
  attn_mfma_kernel<<<dim3(T_SEQ / 64, NH), dim3(256), 0, stream>>>(Q, Kb, Vb, Ab);
  gemm_f32_kernel<<<dim3(C_DIM / 64, T_SEQ / 64), blk, 0, stream>>>(
      Ab, wo, out, T_SEQ, C_DIM, C_DIM);
}

// Round 3
// 284.533 us; speedup vs baseline: 9.2918x; 2.8852x over previous
//
#include <hip/hip_runtime.h>
#include <hip/hip_bf16.h>
#include <math.h>

#define T_SEQ 2048
#define C_DIM 2048
#define NH    32
#define NKV   8
#define DH    64
#define WIN   512

typedef __bf16 bf16x8 __attribute__((ext_vector_type(8)));
typedef __bf16 bf16x4 __attribute__((ext_vector_type(4)));
typedef float  f32x4  __attribute__((ext_vector_type(4)));

__device__ __forceinline__ void gload_lds16(const __bf16* g, __bf16* l) {
  __builtin_amdgcn_global_load_lds(
      (const __attribute__((address_space(1))) void*)g,
      (__attribute__((address_space(3))) void*)l, 16, 0, 0);
}

// ---------------------------------------------------------------------------
// float -> bf16 elementwise convert (4 per thread)
// ---------------------------------------------------------------------------
__global__ void cvt_bf16_kernel(const float* __restrict__ in,
                                __bf16* __restrict__ out, int n4) {
  int i = blockIdx.x * blockDim.x + threadIdx.x;
  if (i >= n4) return;
  float4 v = ((const float4*)in)[i];
  bf16x4 o = {(__bf16)v.x, (__bf16)v.y, (__bf16)v.z, (__bf16)v.w};
  *(bf16x4*)(out + (size_t)i * 4) = o;
}

// ---------------------------------------------------------------------------
// transpose + convert: in[R][Ccols] f32 -> out[Ccols][R] bf16. 32x32 tiles.
// ---------------------------------------------------------------------------
__global__ __launch_bounds__(256) void transpose_bf16_kernel(
    const float* __restrict__ in, __bf16* __restrict__ out, int R, int Ccols) {
  __shared__ float tile[32][33];
  int c0 = blockIdx.x * 32, r0 = blockIdx.y * 32;
  int tx = threadIdx.x, ty = threadIdx.y;  // 32 x 8
#pragma unroll
  for (int i = 0; i < 32; i += 8)
    tile[ty + i][tx] = in[(size_t)(r0 + ty + i) * Ccols + c0 + tx];
  __syncthreads();
#pragma unroll
  for (int i = 0; i < 32; i += 8)
    out[(size_t)(c0 + ty + i) * R + r0 + tx] = (__bf16)tile[tx][ty + i];
}

// ---------------------------------------------------------------------------
// bf16 MFMA GEMM (m97 structure): C[M][N] = A[M][K] * Bt[N][K]^T
// 128x128 tile, BK=32, 256 threads = 4 waves (2x2 of 64x64).
// Staging via global_load_lds width=16 into linear LDS tiles.
// ---------------------------------------------------------------------------
template <typename OutT>
__global__ __launch_bounds__(256) void gemm_bf16_kernel(
    const __bf16* __restrict__ A, const __bf16* __restrict__ Bt,
    OutT* __restrict__ C, int M, int N, int K) {
  __shared__ __bf16 As[128 * 32];  // 8 KB, row-major [row][k]
  __shared__ __bf16 Bs[128 * 32];  // 8 KB, row-major [col][k]

  const int tid = threadIdx.x;
  const int wid = tid >> 6, l = tid & 63;
  const int wr = wid >> 1, wc = wid & 1;  // 2x2 wave grid, 64x64 each
  const int lm = l & 15, lh = l >> 4;
  const int brow = blockIdx.y * 128, bcol = blockIdx.x * 128;

  f32x4 acc[4][4] = {};

  for (int k0 = 0; k0 < K; k0 += 32) {
    __syncthreads();  // previous tile fully consumed
#pragma unroll
    for (int c = 0; c < 2; ++c) {
      int ci = wid + c * 4;            // 8 chunks of 1024B per tile
      int o  = ci * 1024 + l * 16;     // byte offset in tile
      int row = o >> 6;                // 64 B per 32-bf16 row
      int kb  = (o & 63) >> 1;         // bf16 index within row
      gload_lds16(A  + (size_t)(brow + row) * K + k0 + kb, &As[ci * 512]);
      gload_lds16(Bt + (size_t)(bcol + row) * K + k0 + kb, &Bs[ci * 512]);
    }
    __syncthreads();  // compiler drains vmcnt before barrier

    bf16x8 af[4], bfr[4];
#pragma unroll
    for (int i = 0; i < 4; ++i)
      af[i] = *(const bf16x8*)&As[(wr * 64 + i * 16 + lm) * 32 + lh * 8];
#pragma unroll
    for (int j = 0; j < 4; ++j)
      bfr[j] = *(const bf16x8*)&Bs[(wc * 64 + j * 16 + lm) * 32 + lh * 8];
#pragma unroll
    for (int i = 0; i < 4; ++i)
#pragma unroll
      for (int j = 0; j < 4; ++j)
        acc[i][j] = __builtin_amdgcn_mfma_f32_16x16x32_bf16(
            af[i], bfr[j], acc[i][j], 0, 0, 0);
  }

#pragma unroll
  for (int i = 0; i < 4; ++i)
#pragma unroll
    for (int j = 0; j < 4; ++j)
#pragma unroll
      for (int r = 0; r < 4; ++r) {
        int row = brow + wr * 64 + i * 16 + lh * 4 + r;
        int col = bcol + wc * 64 + j * 16 + lm;
        C[(size_t)row * N + col] = (OutT)acc[i][j][r];
      }
}

// ---------------------------------------------------------------------------
// In-place RoPE on bf16 [T][n_heads*64].
// ---------------------------------------------------------------------------
__global__ void rope_kernel(__bf16* __restrict__ X, int n_heads) {
  int idx = blockIdx.x * blockDim.x + threadIdx.x;
  int total = T_SEQ * n_heads * 32;
  if (idx >= total) return;
  int j = idx & 31;
  int h = (idx >> 5) % n_heads;
  int t = idx / (32 * n_heads);
  float inv = powf(10000.0f, -(float)(2 * j) / 64.0f);
  float ang = (float)t * inv;
  float s, c;
  sincosf(ang, &s, &c);
  int base = (t * n_heads + h) * DH + j;
  float a = (float)X[base], b = (float)X[base + 32];
  X[base]      = (__bf16)(a * c - b * s);
  X[base + 32] = (__bf16)(b * c + a * s);
}

// ---------------------------------------------------------------------------
// Flash-style sliding-window GQA attention, bf16 in / bf16 out.
// Block = 4 waves; (head, 64-query tile); each wave 16 queries; key tiles 32.
// ---------------------------------------------------------------------------
__global__ __launch_bounds__(256) void attn_mfma_kernel(
    const __bf16* __restrict__ Q, const __bf16* __restrict__ K,
    const __bf16* __restrict__ V, __bf16* __restrict__ O) {
  __shared__ __bf16 K_lds[32][72];      // [key][d], +8 pad
  __shared__ __bf16 Vt[64][40];         // [d][key], +8 pad
  __shared__ __bf16 P_lds[4][16][40];   // per-wave P tile

  const int tid = threadIdx.x;
  const int l   = tid & 63;
  const int w   = tid >> 6;
  const int q0  = blockIdx.x * 64;
  const int h   = blockIdx.y;
  const int kvh = h >> 2;
  const int q0w = q0 + w * 16;

  const int lm = l & 15;
  const int lh = l >> 4;

  bf16x8 aq0, aq1;
  {
    const __bf16* qp = Q + (size_t)(q0w + lm) * C_DIM + h * DH + lh * 8;
    aq0 = *(const bf16x8*)qp;
    aq1 = *(const bf16x8*)(qp + 32);
  }

  f32x4 o_acc[4] = {};
  float m[4], lsum[4];
#pragma unroll
  for (int r = 0; r < 4; ++r) { m[r] = -1e30f; lsum[r] = 0.0f; }

  const int klo = (q0 - WIN) > 0 ? (q0 - WIN) : 0;
  const int stg_key = tid >> 3;        // 0..31
  const int stg_dp  = (tid & 7) * 8;   // 0..56

  for (int k0 = klo; k0 < q0 + 64; k0 += 32) {
    __syncthreads();
    {
      const __bf16* ks = K + (size_t)(k0 + stg_key) * (NKV * DH) + kvh * DH + stg_dp;
      *(bf16x8*)&K_lds[stg_key][stg_dp] = *(const bf16x8*)ks;
      bf16x8 vv = *(const bf16x8*)(V + (size_t)(k0 + stg_key) * (NKV * DH) + kvh * DH + stg_dp);
#pragma unroll
      for (int j = 0; j < 8; ++j) Vt[stg_dp + j][stg_key] = vv[j];
    }
    __syncthreads();

    if (k0 <= q0w + 15 && k0 + 31 >= q0w - WIN) {
      f32x4 s[2] = {};
#pragma unroll
      for (int kg = 0; kg < 2; ++kg) {
        bf16x8 kb0 = *(const bf16x8*)&K_lds[kg * 16 + lm][lh * 8];
        bf16x8 kb1 = *(const bf16x8*)&K_lds[kg * 16 + lm][32 + lh * 8];
        s[kg] = __builtin_amdgcn_mfma_f32_16x16x32_bf16(aq0, kb0, s[kg], 0, 0, 0);
        s[kg] = __builtin_amdgcn_mfma_f32_16x16x32_bf16(aq1, kb1, s[kg], 0, 0, 0);
      }

      float sv0[4], sv1[4], tmax[4];
#pragma unroll
      for (int r = 0; r < 4; ++r) {
        int qr  = q0w + lh * 4 + r;
        int kc0 = k0 + lm;
        int kc1 = kc0 + 16;
        float a = s[0][r] * 0.125f;
        float b = s[1][r] * 0.125f;
        sv0[r] = (kc0 <= qr && kc0 + WIN >= qr) ? a : -1e30f;
        sv1[r] = (kc1 <= qr && kc1 + WIN >= qr) ? b : -1e30f;
        tmax[r] = fmaxf(sv0[r], sv1[r]);
      }
#pragma unroll
      for (int off = 1; off < 16; off <<= 1)
#pragma unroll
        for (int r = 0; r < 4; ++r)
          tmax[r] = fmaxf(tmax[r], __shfl_xor(tmax[r], off));

      float p0[4], p1[4];
#pragma unroll
      for (int r = 0; r < 4; ++r) {
        float mn = fmaxf(m[r], tmax[r]);
        float co = __expf(m[r] - mn);
        m[r] = mn;
        p0[r] = (sv0[r] > -1e29f) ? __expf(sv0[r] - mn) : 0.0f;
        p1[r] = (sv1[r] > -1e29f) ? __expf(sv1[r] - mn) : 0.0f;
        float ps = p0[r] + p1[r];
#pragma unroll
        for (int off = 1; off < 16; off <<= 1) ps += __shfl_xor(ps, off);
        lsum[r] = lsum[r] * co + ps;
#pragma unroll
        for (int dc = 0; dc < 4; ++dc) o_acc[dc][r] *= co;
      }

#pragma unroll
      for (int r = 0; r < 4; ++r) {
        P_lds[w][lh * 4 + r][lm]      = (__bf16)p0[r];
        P_lds[w][lh * 4 + r][16 + lm] = (__bf16)p1[r];
      }
      bf16x8 pf = *(const bf16x8*)&P_lds[w][lm][lh * 8];

#pragma unroll
      for (int dc = 0; dc < 4; ++dc) {
        bf16x8 vb = *(const bf16x8*)&Vt[dc * 16 + lm][lh * 8];
        o_acc[dc] = __builtin_amdgcn_mfma_f32_16x16x32_bf16(pf, vb, o_acc[dc], 0, 0, 0);
      }
    }
  }

#pragma unroll
  for (int dc = 0; dc < 4; ++dc)
#pragma unroll
    for (int r = 0; r < 4; ++r) {
      int qr = q0w + lh * 4 + r;
      O[(size_t)qr * C_DIM + h * DH + dc * 16 + lm] =
          (__bf16)(o_acc[dc][r] / lsum[r]);
    }
}

// ---------------------------------------------------------------------------
extern "C" void kernel_launch(void* const* d_in, const int* in_sizes, int n_in,
                              void* d_out, int out_size, void* d_ws, size_t ws_size,
                              hipStream_t stream) {
  const float* x  = (const float*)d_in[0];
  const float* wq = (const float*)d_in[1];
  const float* wk = (const float*)d_in[2];
  const float* wv = (const float*)d_in[3];
  const float* wo = (const float*)d_in[4];
  float* out = (float*)d_out;

  // workspace layout (bf16), 48 MB total
  __bf16* xb  = (__bf16*)d_ws;                     // [2048][2048]
  __bf16* wqT = xb  + (size_t)C_DIM * C_DIM;       // [2048][2048]
  __bf16* wkT = wqT + (size_t)C_DIM * C_DIM;       // [512][2048]
  __bf16* wvT = wkT + (size_t)(NKV * DH) * C_DIM;  // [512][2048]
  __bf16* woT = wvT + (size_t)(NKV * DH) * C_DIM;  // [2048][2048]
  __bf16* Qb  = woT + (size_t)C_DIM * C_DIM;       // [2048][2048]
  __bf16* Kb  = Qb  + (size_t)T_SEQ * C_DIM;       // [2048][512]
  __bf16* Vb  = Kb  + (size_t)T_SEQ * NKV * DH;    // [2048][512]
  __bf16* Ab  = Vb  + (size_t)T_SEQ * NKV * DH;    // [2048][2048]

  // converts + transposes
  cvt_bf16_kernel<<<(C_DIM * C_DIM / 4 + 255) / 256, 256, 0, stream>>>(
      x, xb, C_DIM * C_DIM / 4);
  dim3 tb(32, 8);
  transpose_bf16_kernel<<<dim3(C_DIM / 32, C_DIM / 32), tb, 0, stream>>>(
      wq, wqT, C_DIM, C_DIM);
  transpose_bf16_kernel<<<dim3((NKV * DH) / 32, C_DIM / 32), tb, 0, stream>>>(
      wk, wkT, C_DIM, NKV * DH);
  transpose_bf16_kernel<<<dim3((NKV * DH) / 32, C_DIM / 32), tb, 0, stream>>>(
      wv, wvT, C_DIM, NKV * DH);
  transpose_bf16_kernel<<<dim3(C_DIM / 32, C_DIM / 32), tb, 0, stream>>>(
      wo, woT, C_DIM, C_DIM);

  // projections (bf16 out)
  gemm_bf16_kernel<__bf16><<<dim3(C_DIM / 128, T_SEQ / 128), 256, 0, stream>>>(
      xb, wqT, Qb, T_SEQ, C_DIM, C_DIM);
  gemm_bf16_kernel<__bf16><<<dim3((NKV * DH) / 128, T_SEQ / 128), 256, 0, stream>>>(
      xb, wkT, Kb, T_SEQ, NKV * DH, C_DIM);
  gemm_bf16_kernel<__bf16><<<dim3((NKV * DH) / 128, T_SEQ / 128), 256, 0, stream>>>(
      xb, wvT, Vb, T_SEQ, NKV * DH, C_DIM);

  // RoPE in place (bf16)
  rope_kernel<<<(T_SEQ * NH * 32 + 255) / 256, 256, 0, stream>>>(Qb, NH);
  rope_kernel<<<(T_SEQ * NKV * 32 + 255) / 256, 256, 0, stream>>>(Kb, NKV);

  // attention (bf16 in/out)
  attn_mfma_kernel<<<dim3(T_SEQ / 64, NH), dim3(256), 0, stream>>>(Qb, Kb, Vb, Ab);

  // output projection (fp32 out)
  gemm_bf16_kernel<float><<<dim3(C_DIM / 128, T_SEQ / 128), 256, 0, stream>>>(
      Ab, woT, out, T_SEQ, C_DIM, C_DIM);
}

// Round 4
// 171.966 us; speedup vs baseline: 15.3740x; 1.6546x over previous
//
#include <hip/hip_runtime.h>
#include <hip/hip_bf16.h>
#include <math.h>

#define T_SEQ 2048
#define C_DIM 2048
#define NH    32
#define NKV   8
#define DH    64
#define WIN   512
#define QKV_N 3072   // 2048 Q + 512 K + 512 V

typedef __bf16 bf16x8 __attribute__((ext_vector_type(8)));
typedef __bf16 bf16x4 __attribute__((ext_vector_type(4)));
typedef float  f32x4  __attribute__((ext_vector_type(4)));

__device__ __forceinline__ void gload_lds16(const __bf16* g, __bf16* l) {
  __builtin_amdgcn_global_load_lds(
      (const __attribute__((address_space(1))) void*)g,
      (__attribute__((address_space(3))) void*)l, 16, 0, 0);
}

// ---------------------------------------------------------------------------
// float -> bf16 elementwise convert (4 per thread)
// ---------------------------------------------------------------------------
__global__ void cvt_bf16_kernel(const float* __restrict__ in,
                                __bf16* __restrict__ out, int n4) {
  int i = blockIdx.x * blockDim.x + threadIdx.x;
  if (i >= n4) return;
  float4 v = ((const float4*)in)[i];
  bf16x4 o = {(__bf16)v.x, (__bf16)v.y, (__bf16)v.z, (__bf16)v.w};
  *(bf16x4*)(out + (size_t)i * 4) = o;
}

// ---------------------------------------------------------------------------
// RoPE cos/sin table: tab[t*32 + j] = (cos(t*f_j), sin(t*f_j))
// ---------------------------------------------------------------------------
__global__ void rope_table_kernel(float2* __restrict__ tab) {
  int i = blockIdx.x * blockDim.x + threadIdx.x;
  if (i >= T_SEQ * 32) return;
  int j = i & 31, t = i >> 5;
  float inv = powf(10000.0f, -(float)(2 * j) / 64.0f);
  float s, c;
  sincosf((float)t * inv, &s, &c);
  tab[i] = make_float2(c, s);
}

// ---------------------------------------------------------------------------
// transpose + convert: in[R][Ccols] f32 -> out[Ccols][R] bf16. 32x32 tiles.
// ---------------------------------------------------------------------------
__global__ __launch_bounds__(256) void transpose_bf16_kernel(
    const float* __restrict__ in, __bf16* __restrict__ out, int R, int Ccols) {
  __shared__ float tile[32][33];
  int c0 = blockIdx.x * 32, r0 = blockIdx.y * 32;
  int tx = threadIdx.x, ty = threadIdx.y;  // 32 x 8
#pragma unroll
  for (int i = 0; i < 32; i += 8)
    tile[ty + i][tx] = in[(size_t)(r0 + ty + i) * Ccols + c0 + tx];
  __syncthreads();
#pragma unroll
  for (int i = 0; i < 32; i += 8)
    out[(size_t)(c0 + ty + i) * R + r0 + tx] = (__bf16)tile[tx][ty + i];
}

// ---------------------------------------------------------------------------
// bf16 MFMA GEMM (m97 structure): C[M][N] = A[M][K] * Bt[N][K]^T
// 128x128 tile, BK=32, 256 threads = 4 waves (2x2 of 64x64).
// ROPE: fused rotary embedding on the f32 accumulators for cols < 2560
// (Q and K regions of the fused QKV output; each wave's 64-col span is
// exactly one head, pair (d, d+32) lives in (acc[i][j], acc[i][j+2])).
// ---------------------------------------------------------------------------
template <typename OutT, bool ROPE>
__global__ __launch_bounds__(256) void gemm_bf16_kernel(
    const __bf16* __restrict__ A, const __bf16* __restrict__ Bt,
    OutT* __restrict__ C, const float2* __restrict__ rope_tab,
    int M, int N, int K) {
  __shared__ __bf16 As[128 * 32];  // 8 KB, row-major [row][k]
  __shared__ __bf16 Bs[128 * 32];  // 8 KB, row-major [col][k]

  const int tid = threadIdx.x;
  const int wid = tid >> 6, l = tid & 63;
  const int wr = wid >> 1, wc = wid & 1;  // 2x2 wave grid, 64x64 each
  const int lm = l & 15, lh = l >> 4;
  const int brow = blockIdx.y * 128, bcol = blockIdx.x * 128;

  f32x4 acc[4][4] = {};

  for (int k0 = 0; k0 < K; k0 += 32) {
    __syncthreads();
#pragma unroll
    for (int c = 0; c < 2; ++c) {
      int ci = wid + c * 4;            // 8 chunks of 1024B per tile
      int o  = ci * 1024 + l * 16;
      int row = o >> 6;
      int kb  = (o & 63) >> 1;
      gload_lds16(A  + (size_t)(brow + row) * K + k0 + kb, &As[ci * 512]);
      gload_lds16(Bt + (size_t)(bcol + row) * K + k0 + kb, &Bs[ci * 512]);
    }
    __syncthreads();

    bf16x8 af[4], bfr[4];
#pragma unroll
    for (int i = 0; i < 4; ++i)
      af[i] = *(const bf16x8*)&As[(wr * 64 + i * 16 + lm) * 32 + lh * 8];
#pragma unroll
    for (int j = 0; j < 4; ++j)
      bfr[j] = *(const bf16x8*)&Bs[(wc * 64 + j * 16 + lm) * 32 + lh * 8];
#pragma unroll
    for (int i = 0; i < 4; ++i)
#pragma unroll
      for (int j = 0; j < 4; ++j)
        acc[i][j] = __builtin_amdgcn_mfma_f32_16x16x32_bf16(
            af[i], bfr[j], acc[i][j], 0, 0, 0);
  }

  if (ROPE) {
    int colbase = bcol + wc * 64;        // wave-uniform head base
    if (colbase < 2560) {                // Q or K region (V starts at 2560)
#pragma unroll
      for (int i = 0; i < 4; ++i)
#pragma unroll
        for (int r = 0; r < 4; ++r) {
          int t = brow + wr * 64 + i * 16 + lh * 4 + r;
#pragma unroll
          for (int j = 0; j < 2; ++j) {
            float2 cs = rope_tab[t * 32 + j * 16 + lm];
            float v0 = acc[i][j][r], v1 = acc[i][j + 2][r];
            acc[i][j][r]     = v0 * cs.x - v1 * cs.y;
            acc[i][j + 2][r] = v1 * cs.x + v0 * cs.y;
          }
        }
    }
  }

#pragma unroll
  for (int i = 0; i < 4; ++i)
#pragma unroll
    for (int j = 0; j < 4; ++j)
#pragma unroll
      for (int r = 0; r < 4; ++r) {
        int row = brow + wr * 64 + i * 16 + lh * 4 + r;
        int col = bcol + wc * 64 + j * 16 + lm;
        C[(size_t)row * N + col] = (OutT)acc[i][j][r];
      }
}

// ---------------------------------------------------------------------------
// Flash-style sliding-window GQA attention, 64-key tiles.
// Block = 4 waves; (head, 64-query tile); each wave 16 queries.
// Reads fused QKV buffer [T][3072] (Q | K | V), writes Ab [T][2048] bf16.
// ---------------------------------------------------------------------------
__global__ __launch_bounds__(256) void attn_mfma_kernel(
    const __bf16* __restrict__ QKV, __bf16* __restrict__ O) {
  __shared__ __bf16 K_lds[64][72];      // [key][d], +8 pad
  __shared__ __bf16 Vt[64][72];         // [d][key], +8 pad
  __shared__ __bf16 P_lds[4][16][72];   // per-wave P tile [q][k]

  const int tid = threadIdx.x;
  const int l   = tid & 63;
  const int w   = tid >> 6;
  const int q0  = blockIdx.x * 64;
  const int h   = blockIdx.y;
  const int kvh = h >> 2;
  const int q0w = q0 + w * 16;
  const int lm  = l & 15;
  const int lh  = l >> 4;

  const __bf16* Qp = QKV + h * DH;
  const __bf16* Kp = QKV + 2048 + kvh * DH;
  const __bf16* Vp = QKV + 2560 + kvh * DH;

  bf16x8 aq0 = *(const bf16x8*)(Qp + (size_t)(q0w + lm) * QKV_N + lh * 8);
  bf16x8 aq1 = *(const bf16x8*)(Qp + (size_t)(q0w + lm) * QKV_N + 32 + lh * 8);

  f32x4 o_acc[4] = {};
  float m[4], lsum[4];
#pragma unroll
  for (int r = 0; r < 4; ++r) { m[r] = -1e30f; lsum[r] = 0.0f; }

  const int klo  = (q0 - WIN) > 0 ? (q0 - WIN) : 0;
  const int skey = tid >> 2;         // 0..63 (K staging: row per 4 threads)
  const int sdp  = (tid & 3) * 16;   // 0,16,32,48

  for (int k0 = klo; k0 < q0 + 64; k0 += 64) {
    __syncthreads();
    {
      // K tile: row-major, vector writes (coalesced 64B global segments)
      const __bf16* ks = Kp + (size_t)(k0 + skey) * QKV_N + sdp;
      *(bf16x8*)&K_lds[skey][sdp]     = *(const bf16x8*)ks;
      *(bf16x8*)&K_lds[skey][sdp + 8] = *(const bf16x8*)(ks + 8);
      // V tile transposed: lane owns key row l, wave owns d-range w*16..+15.
      // Scalar writes Vt[d][l]: bank (4d + l/2)%32 -> all 32 banks, conflict-free.
      const __bf16* vs = Vp + (size_t)(k0 + l) * QKV_N + w * 16;
      bf16x8 v0 = *(const bf16x8*)vs;
      bf16x8 v1 = *(const bf16x8*)(vs + 8);
#pragma unroll
      for (int j = 0; j < 8; ++j) Vt[w * 16 + j][l]     = v0[j];
#pragma unroll
      for (int j = 0; j < 8; ++j) Vt[w * 16 + 8 + j][l] = v1[j];
    }
    __syncthreads();

    // ---- S = Q K^T: 4 key-groups x 2 d-halves ----
    f32x4 s[4] = {};
#pragma unroll
    for (int kg = 0; kg < 4; ++kg) {
      bf16x8 kb0 = *(const bf16x8*)&K_lds[kg * 16 + lm][lh * 8];
      bf16x8 kb1 = *(const bf16x8*)&K_lds[kg * 16 + lm][32 + lh * 8];
      s[kg] = __builtin_amdgcn_mfma_f32_16x16x32_bf16(aq0, kb0, s[kg], 0, 0, 0);
      s[kg] = __builtin_amdgcn_mfma_f32_16x16x32_bf16(aq1, kb1, s[kg], 0, 0, 0);
    }

    // ---- mask + scale + online softmax ----
    float sv[4][4];
    float tmax[4] = {-1e30f, -1e30f, -1e30f, -1e30f};
#pragma unroll
    for (int kg = 0; kg < 4; ++kg)
#pragma unroll
      for (int r = 0; r < 4; ++r) {
        int qr = q0w + lh * 4 + r;
        int kc = k0 + kg * 16 + lm;
        float a = s[kg][r] * 0.125f;
        sv[kg][r] = (kc <= qr && kc + WIN >= qr) ? a : -1e30f;
        tmax[r] = fmaxf(tmax[r], sv[kg][r]);
      }
#pragma unroll
    for (int off = 1; off < 16; off <<= 1)
#pragma unroll
      for (int r = 0; r < 4; ++r)
        tmax[r] = fmaxf(tmax[r], __shfl_xor(tmax[r], off));

#pragma unroll
    for (int r = 0; r < 4; ++r) {
      float mn = fmaxf(m[r], tmax[r]);
      float co = __expf(m[r] - mn);
      m[r] = mn;
      float ps = 0.0f;
#pragma unroll
      for (int kg = 0; kg < 4; ++kg) {
        float p = (sv[kg][r] > -1e29f) ? __expf(sv[kg][r] - mn) : 0.0f;
        sv[kg][r] = p;
        ps += p;
      }
#pragma unroll
      for (int off = 1; off < 16; off <<= 1) ps += __shfl_xor(ps, off);
      lsum[r] = lsum[r] * co + ps;
#pragma unroll
      for (int dc = 0; dc < 4; ++dc) o_acc[dc][r] *= co;
    }

    // ---- P -> LDS (per-wave), reread as A-fragments ----
#pragma unroll
    for (int kg = 0; kg < 4; ++kg)
#pragma unroll
      for (int r = 0; r < 4; ++r)
        P_lds[w][lh * 4 + r][kg * 16 + lm] = (__bf16)sv[kg][r];
    bf16x8 pf0 = *(const bf16x8*)&P_lds[w][lm][lh * 8];
    bf16x8 pf1 = *(const bf16x8*)&P_lds[w][lm][32 + lh * 8];

    // ---- O += P V: 4 d-chunks x 2 key-halves ----
#pragma unroll
    for (int dc = 0; dc < 4; ++dc) {
      bf16x8 vb0 = *(const bf16x8*)&Vt[dc * 16 + lm][lh * 8];
      bf16x8 vb1 = *(const bf16x8*)&Vt[dc * 16 + lm][32 + lh * 8];
      o_acc[dc] = __builtin_amdgcn_mfma_f32_16x16x32_bf16(pf0, vb0, o_acc[dc], 0, 0, 0);
      o_acc[dc] = __builtin_amdgcn_mfma_f32_16x16x32_bf16(pf1, vb1, o_acc[dc], 0, 0, 0);
    }
  }

#pragma unroll
  for (int dc = 0; dc < 4; ++dc)
#pragma unroll
    for (int r = 0; r < 4; ++r) {
      int qr = q0w + lh * 4 + r;
      O[(size_t)qr * C_DIM + h * DH + dc * 16 + lm] =
          (__bf16)(o_acc[dc][r] / lsum[r]);
    }
}

// ---------------------------------------------------------------------------
extern "C" void kernel_launch(void* const* d_in, const int* in_sizes, int n_in,
                              void* d_out, int out_size, void* d_ws, size_t ws_size,
                              hipStream_t stream) {
  const float* x  = (const float*)d_in[0];
  const float* wq = (const float*)d_in[1];
  const float* wk = (const float*)d_in[2];
  const float* wv = (const float*)d_in[3];
  const float* wo = (const float*)d_in[4];
  float* out = (float*)d_out;

  // workspace layout (40.5 MB)
  __bf16* xb    = (__bf16*)d_ws;                       // [2048][2048] (reused as Ab)
  __bf16* wqkvT = xb + (size_t)C_DIM * C_DIM;          // [3072][2048]
  __bf16* woT   = wqkvT + (size_t)QKV_N * C_DIM;       // [2048][2048]
  __bf16* QKV   = woT + (size_t)C_DIM * C_DIM;         // [2048][3072]
  float2* tab   = (float2*)(QKV + (size_t)T_SEQ * QKV_N);  // [2048*32]
  __bf16* Ab    = xb;  // xb dead after QKV GEMM

  cvt_bf16_kernel<<<(C_DIM * C_DIM / 4 + 255) / 256, 256, 0, stream>>>(
      x, xb, C_DIM * C_DIM / 4);
  rope_table_kernel<<<(T_SEQ * 32 + 255) / 256, 256, 0, stream>>>(tab);

  dim3 tb(32, 8);
  transpose_bf16_kernel<<<dim3(C_DIM / 32, C_DIM / 32), tb, 0, stream>>>(
      wq, wqkvT, C_DIM, C_DIM);
  transpose_bf16_kernel<<<dim3((NKV * DH) / 32, C_DIM / 32), tb, 0, stream>>>(
      wk, wqkvT + (size_t)2048 * C_DIM, C_DIM, NKV * DH);
  transpose_bf16_kernel<<<dim3((NKV * DH) / 32, C_DIM / 32), tb, 0, stream>>>(
      wv, wqkvT + (size_t)2560 * C_DIM, C_DIM, NKV * DH);
  transpose_bf16_kernel<<<dim3(C_DIM / 32, C_DIM / 32), tb, 0, stream>>>(
      wo, woT, C_DIM, C_DIM);

  // fused QKV projection with RoPE epilogue (bf16 out)
  gemm_bf16_kernel<__bf16, true>
      <<<dim3(QKV_N / 128, T_SEQ / 128), 256, 0, stream>>>(
          xb, wqkvT, QKV, tab, T_SEQ, QKV_N, C_DIM);

  // attention (bf16 in/out)
  attn_mfma_kernel<<<dim3(T_SEQ / 64, NH), dim3(256), 0, stream>>>(QKV, Ab);

  // output projection (fp32 out)
  gemm_bf16_kernel<float, false>
      <<<dim3(C_DIM / 128, T_SEQ / 128), 256, 0, stream>>>(
          Ab, woT, out, nullptr, T_SEQ, C_DIM, C_DIM);
}

// Round 6
// 141.753 us; speedup vs baseline: 18.6509x; 1.2131x over previous
//
#include <hip/hip_runtime.h>
#include <hip/hip_bf16.h>
#include <math.h>

#define T_SEQ 2048
#define C_DIM 2048
#define NH    32
#define NKV   8
#define DH    64
#define WIN   512
#define QKV_N 3072   // 2048 Q + 512 K + 512 V

typedef __bf16 bf16x8 __attribute__((ext_vector_type(8)));
typedef __bf16 bf16x4 __attribute__((ext_vector_type(4)));
typedef float  f32x4  __attribute__((ext_vector_type(4)));

__device__ __forceinline__ void gload_lds16(const __bf16* g, __bf16* l) {
  __builtin_amdgcn_global_load_lds(
      (const __attribute__((address_space(1))) void*)g,
      (__attribute__((address_space(3))) void*)l, 16, 0, 0);
}

// ---------------------------------------------------------------------------
// Fused prep: region-dispatched single launch.
//   region 0: cvt x -> xb (bf16)                     4096 blocks
//   region 1: rope cos/sin table                      256 blocks
//   region 2: wq^T  -> wqkvT[0:2048]                 4096 blocks
//   region 3: wk^T  -> wqkvT[2048:2560]              1024 blocks
//   region 4: wv^T  -> wqkvT[2560:3072]              1024 blocks
//   region 5: wo^T  -> woT                           4096 blocks
// ---------------------------------------------------------------------------
__device__ __forceinline__ void tr_tile(const float* __restrict__ in,
                                        __bf16* __restrict__ out,
                                        int R, int Ccols, int tile, int tid,
                                        float (*sh)[33]) {
  int tpc = Ccols >> 5;
  int c0 = (tile % tpc) << 5;
  int r0 = (tile / tpc) << 5;
  int tx = tid & 31, ty = tid >> 5;  // 32 x 8
#pragma unroll
  for (int i = 0; i < 32; i += 8)
    sh[ty + i][tx] = in[(size_t)(r0 + ty + i) * Ccols + c0 + tx];
  __syncthreads();
#pragma unroll
  for (int i = 0; i < 32; i += 8)
    out[(size_t)(c0 + ty + i) * R + r0 + tx] = (__bf16)sh[tx][ty + i];
}

__global__ __launch_bounds__(256) void prep_kernel(
    const float* __restrict__ x, const float* __restrict__ wq,
    const float* __restrict__ wk, const float* __restrict__ wv,
    const float* __restrict__ wo, __bf16* __restrict__ xb,
    __bf16* __restrict__ wqkvT, __bf16* __restrict__ woT,
    float2* __restrict__ tab) {
  __shared__ float sh[32][33];
  int bid = blockIdx.x;
  const int tid = threadIdx.x;
  if (bid < 4096) {  // cvt
    int i = bid * 256 + tid;
    float4 v = ((const float4*)x)[i];
    bf16x4 o = {(__bf16)v.x, (__bf16)v.y, (__bf16)v.z, (__bf16)v.w};
    *(bf16x4*)(xb + (size_t)i * 4) = o;
    return;
  }
  bid -= 4096;
  if (bid < 256) {  // rope table
    int i = bid * 256 + tid;
    int j = i & 31, t = i >> 5;
    float inv = powf(10000.0f, -(float)(2 * j) / 64.0f);
    float s, c;
    sincosf((float)t * inv, &s, &c);
    tab[i] = make_float2(c, s);
    return;
  }
  bid -= 256;
  if (bid < 4096) { tr_tile(wq, wqkvT, C_DIM, C_DIM, bid, tid, sh); return; }
  bid -= 4096;
  if (bid < 1024) {
    tr_tile(wk, wqkvT + (size_t)2048 * C_DIM, C_DIM, NKV * DH, bid, tid, sh);
    return;
  }
  bid -= 1024;
  if (bid < 1024) {
    tr_tile(wv, wqkvT + (size_t)2560 * C_DIM, C_DIM, NKV * DH, bid, tid, sh);
    return;
  }
  bid -= 1024;
  tr_tile(wo, woT, C_DIM, C_DIM, bid, tid, sh);
}

// ---------------------------------------------------------------------------
// bf16 MFMA GEMM: C[M][N] = A[M][K] * Bt[N][K]^T
// 128x64 tile, BK=64, 256 threads = 4 waves (4x1: wave = 32 rows x 64 cols).
// ROPE: fused rotary on f32 accumulators for cols < 2560.
// ---------------------------------------------------------------------------
template <typename OutT, bool ROPE>
__global__ __launch_bounds__(256) void gemm_bf16_kernel(
    const __bf16* __restrict__ A, const __bf16* __restrict__ Bt,
    OutT* __restrict__ C, const float2* __restrict__ rope_tab,
    int M, int N, int K) {
  __shared__ __bf16 As[128 * 64];  // 16 KB, [row][k]
  __shared__ __bf16 Bs[64 * 64];   //  8 KB, [col][k]

  const int tid = threadIdx.x;
  const int wid = tid >> 6, l = tid & 63;
  const int lm = l & 15, lh = l >> 4;
  const int brow = blockIdx.y * 128, bcol = blockIdx.x * 64;

  f32x4 acc[2][4] = {};

  for (int k0 = 0; k0 < K; k0 += 64) {
    __syncthreads();
    // stage A (16 chunks of 1 KB) + B (8 chunks); chunk = 8 rows of 128 B
#pragma unroll
    for (int c = 0; c < 6; ++c) {
      int ci = wid + c * 4;  // 0..23
      int cl = ci < 16 ? ci : ci - 16;
      int o  = cl * 1024 + l * 16;
      int row = o >> 7;
      int kb  = (o & 127) >> 1;
      if (ci < 16)
        gload_lds16(A + (size_t)(brow + row) * K + k0 + kb, &As[ci * 512]);
      else
        gload_lds16(Bt + (size_t)(bcol + row) * K + k0 + kb, &Bs[cl * 512]);
    }
    __syncthreads();

    bf16x8 af[2][2], bfr[4][2];
#pragma unroll
    for (int i = 0; i < 2; ++i)
#pragma unroll
      for (int t = 0; t < 2; ++t)
        af[i][t] = *(const bf16x8*)&As[(wid * 32 + i * 16 + lm) * 64 + t * 32 + lh * 8];
#pragma unroll
    for (int j = 0; j < 4; ++j)
#pragma unroll
      for (int t = 0; t < 2; ++t)
        bfr[j][t] = *(const bf16x8*)&Bs[(j * 16 + lm) * 64 + t * 32 + lh * 8];
#pragma unroll
    for (int t = 0; t < 2; ++t)
#pragma unroll
      for (int i = 0; i < 2; ++i)
#pragma unroll
        for (int j = 0; j < 4; ++j)
          acc[i][j] = __builtin_amdgcn_mfma_f32_16x16x32_bf16(
              af[i][t], bfr[j][t], acc[i][j], 0, 0, 0);
  }

  if (ROPE) {
    if (bcol < 2560) {  // Q or K region (V starts at 2560)
#pragma unroll
      for (int i = 0; i < 2; ++i)
#pragma unroll
        for (int r = 0; r < 4; ++r) {
          int t = brow + wid * 32 + i * 16 + lh * 4 + r;
#pragma unroll
          for (int j = 0; j < 2; ++j) {
            float2 cs = rope_tab[t * 32 + j * 16 + lm];
            float v0 = acc[i][j][r], v1 = acc[i][j + 2][r];
            acc[i][j][r]     = v0 * cs.x - v1 * cs.y;
            acc[i][j + 2][r] = v1 * cs.x + v0 * cs.y;
          }
        }
    }
  }

#pragma unroll
  for (int i = 0; i < 2; ++i)
#pragma unroll
    for (int j = 0; j < 4; ++j)
#pragma unroll
      for (int r = 0; r < 4; ++r) {
        int row = brow + wid * 32 + i * 16 + lh * 4 + r;
        int col = bcol + j * 16 + lm;
        C[(size_t)row * N + col] = (OutT)acc[i][j][r];
      }
}

// ---------------------------------------------------------------------------
// Flash-style sliding-window GQA attention, 64-key tiles.
// Block = 4 waves; (head, 64-query tile); each wave 16 queries.
// R3-proven staging discipline: direct global->LDS between the two barriers,
// unconditional online-softmax rescale. (R4's register prefetch + defer-max
// caused nondeterministic post-timing divergence -> reverted.)
// ---------------------------------------------------------------------------
__global__ __launch_bounds__(256) void attn_mfma_kernel(
    const __bf16* __restrict__ QKV, __bf16* __restrict__ O) {
  __shared__ __bf16 K_lds[64][72];      // [key][d], +8 pad
  __shared__ __bf16 Vt[64][72];         // [d][key], +8 pad
  __shared__ __bf16 P_lds[4][16][72];   // per-wave P tile [q][k]

  const int tid = threadIdx.x;
  const int l   = tid & 63;
  const int w   = tid >> 6;
  const int q0  = blockIdx.x * 64;
  const int h   = blockIdx.y;
  const int kvh = h >> 2;
  const int q0w = q0 + w * 16;
  const int lm  = l & 15;
  const int lh  = l >> 4;

  const __bf16* Qp = QKV + h * DH;
  const __bf16* Kp = QKV + 2048 + kvh * DH;
  const __bf16* Vp = QKV + 2560 + kvh * DH;

  bf16x8 aq0 = *(const bf16x8*)(Qp + (size_t)(q0w + lm) * QKV_N + lh * 8);
  bf16x8 aq1 = *(const bf16x8*)(Qp + (size_t)(q0w + lm) * QKV_N + 32 + lh * 8);

  f32x4 o_acc[4] = {};
  float m[4], lsum[4];
#pragma unroll
  for (int r = 0; r < 4; ++r) { m[r] = -1e30f; lsum[r] = 0.0f; }

  const int klo  = (q0 - WIN) > 0 ? (q0 - WIN) : 0;
  const int skey = tid >> 2;         // 0..63
  const int sdp  = (tid & 3) * 16;   // 0,16,32,48

  for (int k0 = klo; k0 < q0 + 64; k0 += 64) {
    __syncthreads();
    {
      // K tile: row-major, block-cooperative vector writes
      const __bf16* ks = Kp + (size_t)(k0 + skey) * QKV_N + sdp;
      *(bf16x8*)&K_lds[skey][sdp]     = *(const bf16x8*)ks;
      *(bf16x8*)&K_lds[skey][sdp + 8] = *(const bf16x8*)(ks + 8);
      // V tile transposed: lane owns key row l, wave owns d-rows w*16..+15.
      // Scalar writes Vt[d][l]: bank (4d + l/2)%32 -> conflict-free.
      const __bf16* vs = Vp + (size_t)(k0 + l) * QKV_N + w * 16;
      bf16x8 v0 = *(const bf16x8*)vs;
      bf16x8 v1 = *(const bf16x8*)(vs + 8);
#pragma unroll
      for (int j = 0; j < 8; ++j) Vt[w * 16 + j][l]     = v0[j];
#pragma unroll
      for (int j = 0; j < 8; ++j) Vt[w * 16 + 8 + j][l] = v1[j];
    }
    __syncthreads();

    // ---- S = Q K^T: 4 key-groups x 2 d-halves ----
    f32x4 s[4] = {};
#pragma unroll
    for (int kg = 0; kg < 4; ++kg) {
      bf16x8 kb0 = *(const bf16x8*)&K_lds[kg * 16 + lm][lh * 8];
      bf16x8 kb1 = *(const bf16x8*)&K_lds[kg * 16 + lm][32 + lh * 8];
      s[kg] = __builtin_amdgcn_mfma_f32_16x16x32_bf16(aq0, kb0, s[kg], 0, 0, 0);
      s[kg] = __builtin_amdgcn_mfma_f32_16x16x32_bf16(aq1, kb1, s[kg], 0, 0, 0);
    }

    // ---- mask + scale + online softmax (unconditional rescale) ----
    float sv[4][4];
    float tmax[4] = {-1e30f, -1e30f, -1e30f, -1e30f};
#pragma unroll
    for (int kg = 0; kg < 4; ++kg)
#pragma unroll
      for (int r = 0; r < 4; ++r) {
        int qr = q0w + lh * 4 + r;
        int kc = k0 + kg * 16 + lm;
        float a = s[kg][r] * 0.125f;
        sv[kg][r] = (kc <= qr && kc + WIN >= qr) ? a : -1e30f;
        tmax[r] = fmaxf(tmax[r], sv[kg][r]);
      }
#pragma unroll
    for (int off = 1; off < 16; off <<= 1)
#pragma unroll
      for (int r = 0; r < 4; ++r)
        tmax[r] = fmaxf(tmax[r], __shfl_xor(tmax[r], off));

#pragma unroll
    for (int r = 0; r < 4; ++r) {
      float mn = fmaxf(m[r], tmax[r]);
      float co = __expf(m[r] - mn);
      m[r] = mn;
      float ps = 0.0f;
#pragma unroll
      for (int kg = 0; kg < 4; ++kg) {
        float p = (sv[kg][r] > -1e29f) ? __expf(sv[kg][r] - mn) : 0.0f;
        sv[kg][r] = p;
        ps += p;
      }
#pragma unroll
      for (int off = 1; off < 16; off <<= 1) ps += __shfl_xor(ps, off);
      lsum[r] = lsum[r] * co + ps;
#pragma unroll
      for (int dc = 0; dc < 4; ++dc) o_acc[dc][r] *= co;
    }

    // ---- P -> LDS (per-wave), reread as A-fragments ----
#pragma unroll
    for (int kg = 0; kg < 4; ++kg)
#pragma unroll
      for (int r = 0; r < 4; ++r)
        P_lds[w][lh * 4 + r][kg * 16 + lm] = (__bf16)sv[kg][r];
    bf16x8 pf0 = *(const bf16x8*)&P_lds[w][lm][lh * 8];
    bf16x8 pf1 = *(const bf16x8*)&P_lds[w][lm][32 + lh * 8];

    // ---- O += P V: 4 d-chunks x 2 key-halves ----
#pragma unroll
    for (int dc = 0; dc < 4; ++dc) {
      bf16x8 vb0 = *(const bf16x8*)&Vt[dc * 16 + lm][lh * 8];
      bf16x8 vb1 = *(const bf16x8*)&Vt[dc * 16 + lm][32 + lh * 8];
      o_acc[dc] = __builtin_amdgcn_mfma_f32_16x16x32_bf16(pf0, vb0, o_acc[dc], 0, 0, 0);
      o_acc[dc] = __builtin_amdgcn_mfma_f32_16x16x32_bf16(pf1, vb1, o_acc[dc], 0, 0, 0);
    }
  }

#pragma unroll
  for (int dc = 0; dc < 4; ++dc)
#pragma unroll
    for (int r = 0; r < 4; ++r) {
      int qr = q0w + lh * 4 + r;
      O[(size_t)qr * C_DIM + h * DH + dc * 16 + lm] =
          (__bf16)(o_acc[dc][r] / lsum[r]);
    }
}

// ---------------------------------------------------------------------------
extern "C" void kernel_launch(void* const* d_in, const int* in_sizes, int n_in,
                              void* d_out, int out_size, void* d_ws, size_t ws_size,
                              hipStream_t stream) {
  const float* x  = (const float*)d_in[0];
  const float* wq = (const float*)d_in[1];
  const float* wk = (const float*)d_in[2];
  const float* wv = (const float*)d_in[3];
  const float* wo = (const float*)d_in[4];
  float* out = (float*)d_out;

  // workspace layout (40.5 MB)
  __bf16* xb    = (__bf16*)d_ws;                       // [2048][2048] (reused as Ab)
  __bf16* wqkvT = xb + (size_t)C_DIM * C_DIM;          // [3072][2048]
  __bf16* woT   = wqkvT + (size_t)QKV_N * C_DIM;       // [2048][2048]
  __bf16* QKV   = woT + (size_t)C_DIM * C_DIM;         // [2048][3072]
  float2* tab   = (float2*)(QKV + (size_t)T_SEQ * QKV_N);  // [2048*32]
  __bf16* Ab    = xb;  // xb dead after QKV GEMM

  // fused prep: cvt + rope table + 4 transposes (one launch)
  prep_kernel<<<4096 + 256 + 4096 + 1024 + 1024 + 4096, 256, 0, stream>>>(
      x, wq, wk, wv, wo, xb, wqkvT, woT, tab);

  // fused QKV projection with RoPE epilogue (bf16 out)
  gemm_bf16_kernel<__bf16, true>
      <<<dim3(QKV_N / 64, T_SEQ / 128), 256, 0, stream>>>(
          xb, wqkvT, QKV, tab, T_SEQ, QKV_N, C_DIM);

  // attention (bf16 in/out)
  attn_mfma_kernel<<<dim3(T_SEQ / 64, NH), dim3(256), 0, stream>>>(QKV, Ab);

  // output projection (fp32 out)
  gemm_bf16_kernel<float, false>
      <<<dim3(C_DIM / 64, T_SEQ / 128), 256, 0, stream>>>(
          Ab, woT, out, nullptr, T_SEQ, C_DIM, C_DIM);
}

// Round 7
// 125.921 us; speedup vs baseline: 20.9958x; 1.1257x over previous
//
#include <hip/hip_runtime.h>
#include <hip/hip_bf16.h>
#include <math.h>

#define T_SEQ 2048
#define C_DIM 2048
#define NH    32
#define NKV   8
#define DH    64
#define WIN   512
#define QKV_N 3072   // 2048 Q + 512 K + 512 V

typedef __bf16 bf16x8 __attribute__((ext_vector_type(8)));
typedef __bf16 bf16x4 __attribute__((ext_vector_type(4)));
typedef float  f32x4  __attribute__((ext_vector_type(4)));

__device__ __forceinline__ void gload_lds16(const __bf16* g, __bf16* l) {
  __builtin_amdgcn_global_load_lds(
      (const __attribute__((address_space(1))) void*)g,
      (__attribute__((address_space(3))) void*)l, 16, 0, 0);
}

// ---------------------------------------------------------------------------
// Fused prep: region-dispatched single launch (cvt, rope table, 4 transposes).
// ---------------------------------------------------------------------------
__device__ __forceinline__ void tr_tile(const float* __restrict__ in,
                                        __bf16* __restrict__ out,
                                        int R, int Ccols, int tile, int tid,
                                        float (*sh)[33]) {
  int tpc = Ccols >> 5;
  int c0 = (tile % tpc) << 5;
  int r0 = (tile / tpc) << 5;
  int tx = tid & 31, ty = tid >> 5;  // 32 x 8
#pragma unroll
  for (int i = 0; i < 32; i += 8)
    sh[ty + i][tx] = in[(size_t)(r0 + ty + i) * Ccols + c0 + tx];
  __syncthreads();
#pragma unroll
  for (int i = 0; i < 32; i += 8)
    out[(size_t)(c0 + ty + i) * R + r0 + tx] = (__bf16)sh[tx][ty + i];
}

__global__ __launch_bounds__(256) void prep_kernel(
    const float* __restrict__ x, const float* __restrict__ wq,
    const float* __restrict__ wk, const float* __restrict__ wv,
    const float* __restrict__ wo, __bf16* __restrict__ xb,
    __bf16* __restrict__ wqkvT, __bf16* __restrict__ woT,
    float2* __restrict__ tab) {
  __shared__ float sh[32][33];
  int bid = blockIdx.x;
  const int tid = threadIdx.x;
  if (bid < 4096) {  // cvt
    int i = bid * 256 + tid;
    float4 v = ((const float4*)x)[i];
    bf16x4 o = {(__bf16)v.x, (__bf16)v.y, (__bf16)v.z, (__bf16)v.w};
    *(bf16x4*)(xb + (size_t)i * 4) = o;
    return;
  }
  bid -= 4096;
  if (bid < 256) {  // rope table
    int i = bid * 256 + tid;
    int j = i & 31, t = i >> 5;
    float inv = powf(10000.0f, -(float)(2 * j) / 64.0f);
    float s, c;
    sincosf((float)t * inv, &s, &c);
    tab[i] = make_float2(c, s);
    return;
  }
  bid -= 256;
  if (bid < 4096) { tr_tile(wq, wqkvT, C_DIM, C_DIM, bid, tid, sh); return; }
  bid -= 4096;
  if (bid < 1024) {
    tr_tile(wk, wqkvT + (size_t)2048 * C_DIM, C_DIM, NKV * DH, bid, tid, sh);
    return;
  }
  bid -= 1024;
  if (bid < 1024) {
    tr_tile(wv, wqkvT + (size_t)2560 * C_DIM, C_DIM, NKV * DH, bid, tid, sh);
    return;
  }
  bid -= 1024;
  tr_tile(wo, woT, C_DIM, C_DIM, bid, tid, sh);
}

// ---------------------------------------------------------------------------
// bf16 MFMA GEMM: C[M][N] = A[M][K] * Bt[N][K]^T
// 128x64 tile, BK=64, 4 waves (wave = 32 rows x 64 cols).
// Double-buffered LDS, ONE barrier per K-step: issue next-tile gload_lds
// first, compute current tile, then __syncthreads (vmcnt drain overlaps
// compute). T2 XOR-swizzle: LDS(row, chunk c) holds global chunk c^(row&7)
// (inverse-swizzled global source, linear gload_lds dest; read applies the
// same involution) -> ds_read_b128 bank conflicts ~0.
// ROPE: fused rotary on f32 accumulators for cols < 2560.
// ---------------------------------------------------------------------------
template <typename OutT, bool ROPE>
__global__ __launch_bounds__(256) void gemm_bf16_kernel(
    const __bf16* __restrict__ A, const __bf16* __restrict__ Bt,
    OutT* __restrict__ C, const float2* __restrict__ rope_tab,
    int M, int N, int K) {
  __shared__ __bf16 As[2][128 * 64];  // 2 x 16 KB
  __shared__ __bf16 Bs[2][64 * 64];   // 2 x  8 KB

  const int tid = threadIdx.x;
  const int wid = tid >> 6, l = tid & 63;
  const int lm = l & 15, lh = l >> 4;
  const int brow = blockIdx.y * 128, bcol = blockIdx.x * 64;

  // swizzled global k-offset for staging: lane l covers LDS chunk (l&7) of
  // row (l>>3) within its 1KB block; fetch global chunk (l&7)^(l>>3).
  const int kb_swz = (((l & 7) ^ (l >> 3)) << 3);
  const int srow   = l >> 3;  // row within 8-row chunk block

  f32x4 acc[2][4] = {};
  const int NT = K >> 6;

  // prologue: stage tile 0 into buffer 0
#pragma unroll
  for (int c = 0; c < 6; ++c) {
    int ci = wid + c * 4;  // 0..23 (16 A-chunks, 8 B-chunks)
    if (ci < 16) {
      int row = ci * 8 + srow;
      gload_lds16(A + (size_t)(brow + row) * K + kb_swz, &As[0][ci * 512]);
    } else {
      int row = (ci - 16) * 8 + srow;
      gload_lds16(Bt + (size_t)(bcol + row) * K + kb_swz, &Bs[0][(ci - 16) * 512]);
    }
  }
  __syncthreads();

  for (int t = 0; t < NT; ++t) {
    const int cur = t & 1;
    // issue next-tile loads first (latency hides under this tile's compute)
    if (t + 1 < NT) {
      const int k1 = (t + 1) << 6;
#pragma unroll
      for (int c = 0; c < 6; ++c) {
        int ci = wid + c * 4;
        if (ci < 16) {
          int row = ci * 8 + srow;
          gload_lds16(A + (size_t)(brow + row) * K + k1 + kb_swz,
                      &As[cur ^ 1][ci * 512]);
        } else {
          int row = (ci - 16) * 8 + srow;
          gload_lds16(Bt + (size_t)(bcol + row) * K + k1 + kb_swz,
                      &Bs[cur ^ 1][(ci - 16) * 512]);
        }
      }
    }

    // ds_read current tile (swizzled) + MFMA
    const __bf16* as = As[cur];
    const __bf16* bs = Bs[cur];
    const int x7 = lm & 7;
    bf16x8 af[2][2], bfr[4][2];
#pragma unroll
    for (int i = 0; i < 2; ++i)
#pragma unroll
      for (int u = 0; u < 2; ++u)
        af[i][u] = *(const bf16x8*)&as[(wid * 32 + i * 16 + lm) * 64 +
                                       (((u * 4 + lh) ^ x7) << 3)];
#pragma unroll
    for (int j = 0; j < 4; ++j)
#pragma unroll
      for (int u = 0; u < 2; ++u)
        bfr[j][u] = *(const bf16x8*)&bs[(j * 16 + lm) * 64 +
                                        (((u * 4 + lh) ^ x7) << 3)];
#pragma unroll
    for (int u = 0; u < 2; ++u)
#pragma unroll
      for (int i = 0; i < 2; ++i)
#pragma unroll
        for (int j = 0; j < 4; ++j)
          acc[i][j] = __builtin_amdgcn_mfma_f32_16x16x32_bf16(
              af[i][u], bfr[j][u], acc[i][j], 0, 0, 0);

    __syncthreads();  // drains next-tile vmcnt (overlapped with MFMAs above)
  }

  if (ROPE) {
    if (bcol < 2560) {  // Q or K region (V starts at 2560)
#pragma unroll
      for (int i = 0; i < 2; ++i)
#pragma unroll
        for (int r = 0; r < 4; ++r) {
          int t = brow + wid * 32 + i * 16 + lh * 4 + r;
#pragma unroll
          for (int j = 0; j < 2; ++j) {
            float2 cs = rope_tab[t * 32 + j * 16 + lm];
            float v0 = acc[i][j][r], v1 = acc[i][j + 2][r];
            acc[i][j][r]     = v0 * cs.x - v1 * cs.y;
            acc[i][j + 2][r] = v1 * cs.x + v0 * cs.y;
          }
        }
    }
  }

#pragma unroll
  for (int i = 0; i < 2; ++i)
#pragma unroll
    for (int j = 0; j < 4; ++j)
#pragma unroll
      for (int r = 0; r < 4; ++r) {
        int row = brow + wid * 32 + i * 16 + lh * 4 + r;
        int col = bcol + j * 16 + lm;
        C[(size_t)row * N + col] = (OutT)acc[i][j][r];
      }
}

// ---------------------------------------------------------------------------
// Flash-style sliding-window GQA attention, 64-key tiles. (R5-proven)
// ---------------------------------------------------------------------------
__global__ __launch_bounds__(256) void attn_mfma_kernel(
    const __bf16* __restrict__ QKV, __bf16* __restrict__ O) {
  __shared__ __bf16 K_lds[64][72];      // [key][d], +8 pad
  __shared__ __bf16 Vt[64][72];         // [d][key], +8 pad
  __shared__ __bf16 P_lds[4][16][72];   // per-wave P tile [q][k]

  const int tid = threadIdx.x;
  const int l   = tid & 63;
  const int w   = tid >> 6;
  const int q0  = blockIdx.x * 64;
  const int h   = blockIdx.y;
  const int kvh = h >> 2;
  const int q0w = q0 + w * 16;
  const int lm  = l & 15;
  const int lh  = l >> 4;

  const __bf16* Qp = QKV + h * DH;
  const __bf16* Kp = QKV + 2048 + kvh * DH;
  const __bf16* Vp = QKV + 2560 + kvh * DH;

  bf16x8 aq0 = *(const bf16x8*)(Qp + (size_t)(q0w + lm) * QKV_N + lh * 8);
  bf16x8 aq1 = *(const bf16x8*)(Qp + (size_t)(q0w + lm) * QKV_N + 32 + lh * 8);

  f32x4 o_acc[4] = {};
  float m[4], lsum[4];
#pragma unroll
  for (int r = 0; r < 4; ++r) { m[r] = -1e30f; lsum[r] = 0.0f; }

  const int klo  = (q0 - WIN) > 0 ? (q0 - WIN) : 0;
  const int skey = tid >> 2;         // 0..63
  const int sdp  = (tid & 3) * 16;   // 0,16,32,48

  for (int k0 = klo; k0 < q0 + 64; k0 += 64) {
    __syncthreads();
    {
      const __bf16* ks = Kp + (size_t)(k0 + skey) * QKV_N + sdp;
      *(bf16x8*)&K_lds[skey][sdp]     = *(const bf16x8*)ks;
      *(bf16x8*)&K_lds[skey][sdp + 8] = *(const bf16x8*)(ks + 8);
      const __bf16* vs = Vp + (size_t)(k0 + l) * QKV_N + w * 16;
      bf16x8 v0 = *(const bf16x8*)vs;
      bf16x8 v1 = *(const bf16x8*)(vs + 8);
#pragma unroll
      for (int j = 0; j < 8; ++j) Vt[w * 16 + j][l]     = v0[j];
#pragma unroll
      for (int j = 0; j < 8; ++j) Vt[w * 16 + 8 + j][l] = v1[j];
    }
    __syncthreads();

    f32x4 s[4] = {};
#pragma unroll
    for (int kg = 0; kg < 4; ++kg) {
      bf16x8 kb0 = *(const bf16x8*)&K_lds[kg * 16 + lm][lh * 8];
      bf16x8 kb1 = *(const bf16x8*)&K_lds[kg * 16 + lm][32 + lh * 8];
      s[kg] = __builtin_amdgcn_mfma_f32_16x16x32_bf16(aq0, kb0, s[kg], 0, 0, 0);
      s[kg] = __builtin_amdgcn_mfma_f32_16x16x32_bf16(aq1, kb1, s[kg], 0, 0, 0);
    }

    float sv[4][4];
    float tmax[4] = {-1e30f, -1e30f, -1e30f, -1e30f};
#pragma unroll
    for (int kg = 0; kg < 4; ++kg)
#pragma unroll
      for (int r = 0; r < 4; ++r) {
        int qr = q0w + lh * 4 + r;
        int kc = k0 + kg * 16 + lm;
        float a = s[kg][r] * 0.125f;
        sv[kg][r] = (kc <= qr && kc + WIN >= qr) ? a : -1e30f;
        tmax[r] = fmaxf(tmax[r], sv[kg][r]);
      }
#pragma unroll
    for (int off = 1; off < 16; off <<= 1)
#pragma unroll
      for (int r = 0; r < 4; ++r)
        tmax[r] = fmaxf(tmax[r], __shfl_xor(tmax[r], off));

#pragma unroll
    for (int r = 0; r < 4; ++r) {
      float mn = fmaxf(m[r], tmax[r]);
      float co = __expf(m[r] - mn);
      m[r] = mn;
      float ps = 0.0f;
#pragma unroll
      for (int kg = 0; kg < 4; ++kg) {
        float p = (sv[kg][r] > -1e29f) ? __expf(sv[kg][r] - mn) : 0.0f;
        sv[kg][r] = p;
        ps += p;
      }
#pragma unroll
      for (int off = 1; off < 16; off <<= 1) ps += __shfl_xor(ps, off);
      lsum[r] = lsum[r] * co + ps;
#pragma unroll
      for (int dc = 0; dc < 4; ++dc) o_acc[dc][r] *= co;
    }

#pragma unroll
    for (int kg = 0; kg < 4; ++kg)
#pragma unroll
      for (int r = 0; r < 4; ++r)
        P_lds[w][lh * 4 + r][kg * 16 + lm] = (__bf16)sv[kg][r];
    bf16x8 pf0 = *(const bf16x8*)&P_lds[w][lm][lh * 8];
    bf16x8 pf1 = *(const bf16x8*)&P_lds[w][lm][32 + lh * 8];

#pragma unroll
    for (int dc = 0; dc < 4; ++dc) {
      bf16x8 vb0 = *(const bf16x8*)&Vt[dc * 16 + lm][lh * 8];
      bf16x8 vb1 = *(const bf16x8*)&Vt[dc * 16 + lm][32 + lh * 8];
      o_acc[dc] = __builtin_amdgcn_mfma_f32_16x16x32_bf16(pf0, vb0, o_acc[dc], 0, 0, 0);
      o_acc[dc] = __builtin_amdgcn_mfma_f32_16x16x32_bf16(pf1, vb1, o_acc[dc], 0, 0, 0);
    }
  }

#pragma unroll
  for (int dc = 0; dc < 4; ++dc)
#pragma unroll
    for (int r = 0; r < 4; ++r) {
      int qr = q0w + lh * 4 + r;
      O[(size_t)qr * C_DIM + h * DH + dc * 16 + lm] =
          (__bf16)(o_acc[dc][r] / lsum[r]);
    }
}

// ---------------------------------------------------------------------------
extern "C" void kernel_launch(void* const* d_in, const int* in_sizes, int n_in,
                              void* d_out, int out_size, void* d_ws, size_t ws_size,
                              hipStream_t stream) {
  const float* x  = (const float*)d_in[0];
  const float* wq = (const float*)d_in[1];
  const float* wk = (const float*)d_in[2];
  const float* wv = (const float*)d_in[3];
  const float* wo = (const float*)d_in[4];
  float* out = (float*)d_out;

  // workspace layout (40.5 MB)
  __bf16* xb    = (__bf16*)d_ws;                       // [2048][2048] (reused as Ab)
  __bf16* wqkvT = xb + (size_t)C_DIM * C_DIM;          // [3072][2048]
  __bf16* woT   = wqkvT + (size_t)QKV_N * C_DIM;       // [2048][2048]
  __bf16* QKV   = woT + (size_t)C_DIM * C_DIM;         // [2048][3072]
  float2* tab   = (float2*)(QKV + (size_t)T_SEQ * QKV_N);  // [2048*32]
  __bf16* Ab    = xb;  // xb dead after QKV GEMM

  prep_kernel<<<4096 + 256 + 4096 + 1024 + 1024 + 4096, 256, 0, stream>>>(
      x, wq, wk, wv, wo, xb, wqkvT, woT, tab);

  gemm_bf16_kernel<__bf16, true>
      <<<dim3(QKV_N / 64, T_SEQ / 128), 256, 0, stream>>>(
          xb, wqkvT, QKV, tab, T_SEQ, QKV_N, C_DIM);

  attn_mfma_kernel<<<dim3(T_SEQ / 64, NH), dim3(256), 0, stream>>>(QKV, Ab);

  gemm_bf16_kernel<float, false>
      <<<dim3(C_DIM / 64, T_SEQ / 128), 256, 0, stream>>>(
          Ab, woT, out, nullptr, T_SEQ, C_DIM, C_DIM);
}

// Round 8
// 114.795 us; speedup vs baseline: 23.0308x; 1.0969x over previous
//
#include <hip/hip_runtime.h>
#include <hip/hip_bf16.h>
#include <math.h>

#define T_SEQ 2048
#define C_DIM 2048
#define NH    32
#define NKV   8
#define DH    64
#define WIN   512
#define QKV_N 3072   // 2048 Q + 512 K + 512 V

typedef __bf16 bf16x8 __attribute__((ext_vector_type(8)));
typedef __bf16 bf16x4 __attribute__((ext_vector_type(4)));
typedef float  f32x4  __attribute__((ext_vector_type(4)));

#if __has_builtin(__builtin_amdgcn_exp2f)
#define EXP2(x) __builtin_amdgcn_exp2f(x)
#else
#define EXP2(x) exp2f(x)
#endif

__device__ __forceinline__ void gload_lds16(const __bf16* g, __bf16* l) {
  __builtin_amdgcn_global_load_lds(
      (const __attribute__((address_space(1))) void*)g,
      (__attribute__((address_space(3))) void*)l, 16, 0, 0);
}

// ---------------------------------------------------------------------------
// Fused prep: region-dispatched single launch (cvt, rope table, 4 transposes).
// ---------------------------------------------------------------------------
__device__ __forceinline__ void tr_tile(const float* __restrict__ in,
                                        __bf16* __restrict__ out,
                                        int R, int Ccols, int tile, int tid,
                                        float (*sh)[33]) {
  int tpc = Ccols >> 5;
  int c0 = (tile % tpc) << 5;
  int r0 = (tile / tpc) << 5;
  int tx = tid & 31, ty = tid >> 5;  // 32 x 8
#pragma unroll
  for (int i = 0; i < 32; i += 8)
    sh[ty + i][tx] = in[(size_t)(r0 + ty + i) * Ccols + c0 + tx];
  __syncthreads();
#pragma unroll
  for (int i = 0; i < 32; i += 8)
    out[(size_t)(c0 + ty + i) * R + r0 + tx] = (__bf16)sh[tx][ty + i];
}

__global__ __launch_bounds__(256) void prep_kernel(
    const float* __restrict__ x, const float* __restrict__ wq,
    const float* __restrict__ wk, const float* __restrict__ wv,
    const float* __restrict__ wo, __bf16* __restrict__ xb,
    __bf16* __restrict__ wqkvT, __bf16* __restrict__ woT,
    float2* __restrict__ tab) {
  __shared__ float sh[32][33];
  int bid = blockIdx.x;
  const int tid = threadIdx.x;
  if (bid < 4096) {  // cvt
    int i = bid * 256 + tid;
    float4 v = ((const float4*)x)[i];
    bf16x4 o = {(__bf16)v.x, (__bf16)v.y, (__bf16)v.z, (__bf16)v.w};
    *(bf16x4*)(xb + (size_t)i * 4) = o;
    return;
  }
  bid -= 4096;
  if (bid < 256) {  // rope table
    int i = bid * 256 + tid;
    int j = i & 31, t = i >> 5;
    float inv = powf(10000.0f, -(float)(2 * j) / 64.0f);
    float s, c;
    sincosf((float)t * inv, &s, &c);
    tab[i] = make_float2(c, s);
    return;
  }
  bid -= 256;
  if (bid < 4096) { tr_tile(wq, wqkvT, C_DIM, C_DIM, bid, tid, sh); return; }
  bid -= 4096;
  if (bid < 1024) {
    tr_tile(wk, wqkvT + (size_t)2048 * C_DIM, C_DIM, NKV * DH, bid, tid, sh);
    return;
  }
  bid -= 1024;
  if (bid < 1024) {
    tr_tile(wv, wqkvT + (size_t)2560 * C_DIM, C_DIM, NKV * DH, bid, tid, sh);
    return;
  }
  bid -= 1024;
  tr_tile(wo, woT, C_DIM, C_DIM, bid, tid, sh);
}

// ---------------------------------------------------------------------------
// bf16 MFMA GEMM: C[M][N] = A[M][K] * Bt[N][K]^T
// 128x64 tile, BK=64, double-buffered LDS, one barrier per K-step,
// XOR-swizzled LDS (R6-proven). ROPE epilogue also pre-scales the Q region
// by 0.125*log2(e) so attention softmax can run in exp2 domain.
// ---------------------------------------------------------------------------
template <typename OutT, bool ROPE>
__global__ __launch_bounds__(256) void gemm_bf16_kernel(
    const __bf16* __restrict__ A, const __bf16* __restrict__ Bt,
    OutT* __restrict__ C, const float2* __restrict__ rope_tab,
    int M, int N, int K) {
  __shared__ __bf16 As[2][128 * 64];  // 2 x 16 KB
  __shared__ __bf16 Bs[2][64 * 64];   // 2 x  8 KB

  const int tid = threadIdx.x;
  const int wid = tid >> 6, l = tid & 63;
  const int lm = l & 15, lh = l >> 4;
  const int brow = blockIdx.y * 128, bcol = blockIdx.x * 64;

  const int kb_swz = (((l & 7) ^ (l >> 3)) << 3);
  const int srow   = l >> 3;

  f32x4 acc[2][4] = {};
  const int NT = K >> 6;

#pragma unroll
  for (int c = 0; c < 6; ++c) {
    int ci = wid + c * 4;
    if (ci < 16) {
      int row = ci * 8 + srow;
      gload_lds16(A + (size_t)(brow + row) * K + kb_swz, &As[0][ci * 512]);
    } else {
      int row = (ci - 16) * 8 + srow;
      gload_lds16(Bt + (size_t)(bcol + row) * K + kb_swz, &Bs[0][(ci - 16) * 512]);
    }
  }
  __syncthreads();

  for (int t = 0; t < NT; ++t) {
    const int cur = t & 1;
    if (t + 1 < NT) {
      const int k1 = (t + 1) << 6;
#pragma unroll
      for (int c = 0; c < 6; ++c) {
        int ci = wid + c * 4;
        if (ci < 16) {
          int row = ci * 8 + srow;
          gload_lds16(A + (size_t)(brow + row) * K + k1 + kb_swz,
                      &As[cur ^ 1][ci * 512]);
        } else {
          int row = (ci - 16) * 8 + srow;
          gload_lds16(Bt + (size_t)(bcol + row) * K + k1 + kb_swz,
                      &Bs[cur ^ 1][(ci - 16) * 512]);
        }
      }
    }

    const __bf16* as = As[cur];
    const __bf16* bs = Bs[cur];
    const int x7 = lm & 7;
    bf16x8 af[2][2], bfr[4][2];
#pragma unroll
    for (int i = 0; i < 2; ++i)
#pragma unroll
      for (int u = 0; u < 2; ++u)
        af[i][u] = *(const bf16x8*)&as[(wid * 32 + i * 16 + lm) * 64 +
                                       (((u * 4 + lh) ^ x7) << 3)];
#pragma unroll
    for (int j = 0; j < 4; ++j)
#pragma unroll
      for (int u = 0; u < 2; ++u)
        bfr[j][u] = *(const bf16x8*)&bs[(j * 16 + lm) * 64 +
                                        (((u * 4 + lh) ^ x7) << 3)];
#pragma unroll
    for (int u = 0; u < 2; ++u)
#pragma unroll
      for (int i = 0; i < 2; ++i)
#pragma unroll
        for (int j = 0; j < 4; ++j)
          acc[i][j] = __builtin_amdgcn_mfma_f32_16x16x32_bf16(
              af[i][u], bfr[j][u], acc[i][j], 0, 0, 0);

    __syncthreads();
  }

  if (ROPE) {
    if (bcol < 2560) {  // Q or K region (V starts at 2560)
#pragma unroll
      for (int i = 0; i < 2; ++i)
#pragma unroll
        for (int r = 0; r < 4; ++r) {
          int t = brow + wid * 32 + i * 16 + lh * 4 + r;
#pragma unroll
          for (int j = 0; j < 2; ++j) {
            float2 cs = rope_tab[t * 32 + j * 16 + lm];
            float v0 = acc[i][j][r], v1 = acc[i][j + 2][r];
            acc[i][j][r]     = v0 * cs.x - v1 * cs.y;
            acc[i][j + 2][r] = v1 * cs.x + v0 * cs.y;
          }
        }
    }
    if (bcol < 2048) {  // Q region: fold softmax scale (1/8 * log2 e)
#pragma unroll
      for (int i = 0; i < 2; ++i)
#pragma unroll
        for (int j = 0; j < 4; ++j)
#pragma unroll
          for (int r = 0; r < 4; ++r) acc[i][j][r] *= 0.18033688f;
    }
  }

#pragma unroll
  for (int i = 0; i < 2; ++i)
#pragma unroll
    for (int j = 0; j < 4; ++j)
#pragma unroll
      for (int r = 0; r < 4; ++r) {
        int row = brow + wid * 32 + i * 16 + lh * 4 + r;
        int col = bcol + j * 16 + lm;
        C[(size_t)row * N + col] = (OutT)acc[i][j][r];
      }
}

// ---------------------------------------------------------------------------
// Flash-style sliding-window GQA attention, 64-key tiles, swapped-operand
// QK^T (T12): S^T = mfma(K, Q) puts a full query-row in-lane -> scalar
// m/lsum, 15 in-lane fmax + 2 shfl per reduce. PV computes O^T = V^T P^T
// with the SAME operand register layouts as before. Q arrives pre-scaled by
// 0.125*log2e, softmax in exp2 domain; masked scores underflow naturally.
// Staging/barrier discipline identical to R6 (proven deterministic).
// ---------------------------------------------------------------------------
__global__ __launch_bounds__(256) void attn_mfma_kernel(
    const __bf16* __restrict__ QKV, __bf16* __restrict__ O) {
  __shared__ __bf16 K_lds[64][72];      // [key][d], +8 pad
  __shared__ __bf16 Vt[64][72];         // [d][key], +8 pad
  __shared__ __bf16 P_lds[4][16][72];   // per-wave P tile [q][k]

  const int tid = threadIdx.x;
  const int l   = tid & 63;
  const int w   = tid >> 6;
  const int q0  = blockIdx.x * 64;
  const int h   = blockIdx.y;
  const int kvh = h >> 2;
  const int q0w = q0 + w * 16;
  const int lm  = l & 15;
  const int lh  = l >> 4;

  const __bf16* Qp = QKV + h * DH;
  const __bf16* Kp = QKV + 2048 + kvh * DH;
  const __bf16* Vp = QKV + 2560 + kvh * DH;

  bf16x8 aq0 = *(const bf16x8*)(Qp + (size_t)(q0w + lm) * QKV_N + lh * 8);
  bf16x8 aq1 = *(const bf16x8*)(Qp + (size_t)(q0w + lm) * QKV_N + 32 + lh * 8);

  f32x4 o_acc[4] = {};
  float m = -60.0f, lsum = 0.0f;   // log2 domain

  const int klo  = (q0 - WIN) > 0 ? (q0 - WIN) : 0;
  const int skey = tid >> 2;         // 0..63
  const int sdp  = (tid & 3) * 16;   // 0,16,32,48

  for (int k0 = klo; k0 < q0 + 64; k0 += 64) {
    __syncthreads();
    {
      const __bf16* ks = Kp + (size_t)(k0 + skey) * QKV_N + sdp;
      *(bf16x8*)&K_lds[skey][sdp]     = *(const bf16x8*)ks;
      *(bf16x8*)&K_lds[skey][sdp + 8] = *(const bf16x8*)(ks + 8);
      const __bf16* vs = Vp + (size_t)(k0 + l) * QKV_N + w * 16;
      bf16x8 v0 = *(const bf16x8*)vs;
      bf16x8 v1 = *(const bf16x8*)(vs + 8);
#pragma unroll
      for (int j = 0; j < 8; ++j) Vt[w * 16 + j][l]     = v0[j];
#pragma unroll
      for (int j = 0; j < 8; ++j) Vt[w * 16 + 8 + j][l] = v1[j];
    }
    __syncthreads();

    // ---- S^T = K Q^T: lane (lh,lm) holds S[k0+kg*16+lh*4+r][q0w+lm] ----
    f32x4 s[4] = {};
#pragma unroll
    for (int kg = 0; kg < 4; ++kg) {
      bf16x8 kb0 = *(const bf16x8*)&K_lds[kg * 16 + lm][lh * 8];
      bf16x8 kb1 = *(const bf16x8*)&K_lds[kg * 16 + lm][32 + lh * 8];
      s[kg] = __builtin_amdgcn_mfma_f32_16x16x32_bf16(kb0, aq0, s[kg], 0, 0, 0);
      s[kg] = __builtin_amdgcn_mfma_f32_16x16x32_bf16(kb1, aq1, s[kg], 0, 0, 0);
    }

    // ---- mask (interior fast path) ----
    float sv[4][4];
    const bool full = (k0 + 63 <= q0w) && (k0 >= q0w + 15 - WIN);
    if (full) {
#pragma unroll
      for (int kg = 0; kg < 4; ++kg)
#pragma unroll
        for (int r = 0; r < 4; ++r) sv[kg][r] = s[kg][r];
    } else {
      const int qr = q0w + lm;
#pragma unroll
      for (int kg = 0; kg < 4; ++kg)
#pragma unroll
        for (int r = 0; r < 4; ++r) {
          int kc = k0 + kg * 16 + lh * 4 + r;
          sv[kg][r] = (kc <= qr && kc + WIN >= qr) ? s[kg][r] : -1e30f;
        }
    }

    // ---- in-lane row max + 2-lane-hop reduce ----
    float t01 = fmaxf(fmaxf(fmaxf(sv[0][0], sv[0][1]), fmaxf(sv[0][2], sv[0][3])),
                      fmaxf(fmaxf(sv[1][0], sv[1][1]), fmaxf(sv[1][2], sv[1][3])));
    float t23 = fmaxf(fmaxf(fmaxf(sv[2][0], sv[2][1]), fmaxf(sv[2][2], sv[2][3])),
                      fmaxf(fmaxf(sv[3][0], sv[3][1]), fmaxf(sv[3][2], sv[3][3])));
    float tmax = fmaxf(t01, t23);
    tmax = fmaxf(tmax, __shfl_xor(tmax, 16));
    tmax = fmaxf(tmax, __shfl_xor(tmax, 32));

    float mn = fmaxf(m, tmax);
    float co = EXP2(m - mn);
    m = mn;
    float ps = 0.0f;
#pragma unroll
    for (int kg = 0; kg < 4; ++kg)
#pragma unroll
      for (int r = 0; r < 4; ++r) {
        float p = EXP2(sv[kg][r] - mn);  // masked: exp2(-huge) -> 0
        sv[kg][r] = p;
        ps += p;
      }
    ps += __shfl_xor(ps, 16);
    ps += __shfl_xor(ps, 32);
    lsum = lsum * co + ps;
#pragma unroll
    for (int dc = 0; dc < 4; ++dc)
#pragma unroll
      for (int r = 0; r < 4; ++r) o_acc[dc][r] *= co;

    // ---- P -> LDS in [q][k] layout, reread as b128 fragments ----
#pragma unroll
    for (int kg = 0; kg < 4; ++kg)
#pragma unroll
      for (int r = 0; r < 4; ++r)
        P_lds[w][lm][kg * 16 + lh * 4 + r] = (__bf16)sv[kg][r];
    bf16x8 pf0 = *(const bf16x8*)&P_lds[w][lm][lh * 8];
    bf16x8 pf1 = *(const bf16x8*)&P_lds[w][lm][32 + lh * 8];

    // ---- O^T += V^T P^T: lane holds O[q0w+lm][dc*16+lh*4+r] ----
#pragma unroll
    for (int dc = 0; dc < 4; ++dc) {
      bf16x8 vb0 = *(const bf16x8*)&Vt[dc * 16 + lm][lh * 8];
      bf16x8 vb1 = *(const bf16x8*)&Vt[dc * 16 + lm][32 + lh * 8];
      o_acc[dc] = __builtin_amdgcn_mfma_f32_16x16x32_bf16(vb0, pf0, o_acc[dc], 0, 0, 0);
      o_acc[dc] = __builtin_amdgcn_mfma_f32_16x16x32_bf16(vb1, pf1, o_acc[dc], 0, 0, 0);
    }
  }

  const float inv = 1.0f / lsum;
#pragma unroll
  for (int dc = 0; dc < 4; ++dc) {
    bf16x4 ov;
#pragma unroll
    for (int r = 0; r < 4; ++r) ov[r] = (__bf16)(o_acc[dc][r] * inv);
    *(bf16x4*)&O[(size_t)(q0w + lm) * C_DIM + h * DH + dc * 16 + lh * 4] = ov;
  }
}

// ---------------------------------------------------------------------------
extern "C" void kernel_launch(void* const* d_in, const int* in_sizes, int n_in,
                              void* d_out, int out_size, void* d_ws, size_t ws_size,
                              hipStream_t stream) {
  const float* x  = (const float*)d_in[0];
  const float* wq = (const float*)d_in[1];
  const float* wk = (const float*)d_in[2];
  const float* wv = (const float*)d_in[3];
  const float* wo = (const float*)d_in[4];
  float* out = (float*)d_out;

  // workspace layout (40.5 MB)
  __bf16* xb    = (__bf16*)d_ws;                       // [2048][2048] (reused as Ab)
  __bf16* wqkvT = xb + (size_t)C_DIM * C_DIM;          // [3072][2048]
  __bf16* woT   = wqkvT + (size_t)QKV_N * C_DIM;       // [2048][2048]
  __bf16* QKV   = woT + (size_t)C_DIM * C_DIM;         // [2048][3072]
  float2* tab   = (float2*)(QKV + (size_t)T_SEQ * QKV_N);  // [2048*32]
  __bf16* Ab    = xb;  // xb dead after QKV GEMM

  prep_kernel<<<4096 + 256 + 4096 + 1024 + 1024 + 4096, 256, 0, stream>>>(
      x, wq, wk, wv, wo, xb, wqkvT, woT, tab);

  gemm_bf16_kernel<__bf16, true>
      <<<dim3(QKV_N / 64, T_SEQ / 128), 256, 0, stream>>>(
          xb, wqkvT, QKV, tab, T_SEQ, QKV_N, C_DIM);

  attn_mfma_kernel<<<dim3(T_SEQ / 64, NH), dim3(256), 0, stream>>>(QKV, Ab);

  gemm_bf16_kernel<float, false>
      <<<dim3(C_DIM / 64, T_SEQ / 128), 256, 0, stream>>>(
          Ab, woT, out, nullptr, T_SEQ, C_DIM, C_DIM);
}